// Round 4
// baseline (24008.717 us; speedup 1.0000x reference)
//
#include <hip/hip_runtime.h>
#include <math.h>

#define B_ 128
#define T_ 128
#define IN_ 75
#define H_ 512
#define C_ 60
#define Q_ 25

// ---------------- workspace layout (bytes) ----------------
constexpr size_t OFF_WXTP = 0;         // uint4 [ug][k2] bf16 pairs {W_x_t,W_h_t,W_x_s,W_h_s} (lo=k,hi=k+1)
constexpr size_t OFF_WIHP = 2097152;   // uint4 [ug][k]  bf16 {it|ft, gt|ot, is|fs, gs|os}
constexpr size_t OFF_FTP  = 2711552;   // uint  [ug][k]  bf16 {fct|fc1}
constexpr size_t OFF_W1P  = 2865152;   // uint2 [ug][k]  bf16 {i1|f1, g1|o1}
constexpr size_t OFF_U2   = 3172352;   // float [25][512]  (U_s @ fc2_w.T)
constexpr size_t OFF_B2   = 3223552;   // float [32]
constexpr size_t OFF_SPA  = 3223680;   // float4 [k=unit][bg] {h_t,h_s,tmp1,tmp2}
constexpr size_t OFF_H1   = 4272256;   // float2 [k2][bg] {h1(2k2),h1(2k2+1)}
constexpr size_t OFF_ST   = 4534400;   // float [b][j]
constexpr size_t OFF_FLG  = 4796544;   // unsigned flags, 256 x 64B
constexpr size_t WS_BYTES = 4812928;

struct Full {
  const float* inputs;
  const float* Wih_t; const float* Whh_t; const float* bih_t; const float* bhh_t;
  const float* Wih_s; const float* Whh_s; const float* bih_s; const float* bhh_s;
  const float* Wih_1; const float* Whh_1; const float* bih_1; const float* bhh_1;
  const float* fc_w;  const float* fc_b;
  const float* fct_w; const float* fct_b;
  const float* fc1_w; const float* fc1_b;
  const float* fc2_w; const float* fc2_b;
  const float* W_x_t; const float* W_h_t; const float* b_t;
  const float* W_x_s; const float* W_h_s; const float* U_s; const float* b_s; const float* b_us;
  char* ws; float* out;
};

__device__ __forceinline__ float sigm(float v) { return 1.f / (1.f + expf(-v)); }
__device__ __forceinline__ float blo(unsigned d) { return __uint_as_float(d << 16); }
__device__ __forceinline__ float bhi(unsigned d) { return __uint_as_float(d & 0xffff0000u); }
__device__ __forceinline__ unsigned short tob(float f) {
  unsigned u = __float_as_uint(f);
  return (unsigned short)((u + 0x7fffu + ((u >> 16) & 1u)) >> 16);
}
__device__ __forceinline__ unsigned pack2(float lo, float hi) {
  return (unsigned)tob(lo) | ((unsigned)tob(hi) << 16);
}

// ---------------- prep: pack weights ----------------
__global__ void prep_pack(Full f) {
  uint4* WXTP = (uint4*)(f.ws + OFF_WXTP);
  uint4* WIHP = (uint4*)(f.ws + OFF_WIHP);
  unsigned* FTP = (unsigned*)(f.ws + OFF_FTP);
  uint2* W1P = (uint2*)(f.ws + OFF_W1P);
  float* U2 = (float*)(f.ws + OFF_U2);
  float* B2 = (float*)(f.ws + OFF_B2);
  unsigned* FLG = (unsigned*)(f.ws + OFF_FLG);
  // zero barrier flags every launch (deterministic across graph replays)
  for (int i = blockIdx.x * blockDim.x + threadIdx.x; i < 4096; i += gridDim.x * blockDim.x)
    FLG[i] = 0u;

  const size_t N1 = (size_t)512 * 256;   // WXTP (ug,k2)
  const size_t N2 = (size_t)512 * 75;    // WIHP
  const size_t N3 = (size_t)512 * 75;    // FTP
  const size_t N4 = (size_t)512 * 75;    // W1P
  const size_t N5 = (size_t)25 * 512;    // U2
  const size_t N6 = 25;                  // B2
  const size_t TOT = N1 + N2 + N3 + N4 + N5 + N6;
  for (size_t i = (size_t)blockIdx.x * blockDim.x + threadIdx.x; i < TOT;
       i += (size_t)gridDim.x * blockDim.x) {
    if (i < N1) {
      size_t ug = i >> 8, k2 = i & 255; size_t k = k2 * 2;
      uint4 v;
      v.x = pack2(f.W_x_t[k * 512 + ug], f.W_x_t[(k + 1) * 512 + ug]);
      v.y = pack2(f.W_h_t[k * 512 + ug], f.W_h_t[(k + 1) * 512 + ug]);
      v.z = pack2(f.W_x_s[k * 512 + ug], f.W_x_s[(k + 1) * 512 + ug]);
      v.w = pack2(f.W_h_s[k * 512 + ug], f.W_h_s[(k + 1) * 512 + ug]);
      WXTP[ug * 256 + k2] = v;
    } else if (i < N1 + N2) {
      size_t j = i - N1; size_t ug = j / 75, k = j % 75;
      uint4 v;
      v.x = pack2(f.Wih_t[ug * 75 + k],          f.Wih_t[(512 + ug) * 75 + k]);
      v.y = pack2(f.Wih_t[(1024 + ug) * 75 + k], f.Wih_t[(1536 + ug) * 75 + k]);
      v.z = pack2(f.Wih_s[ug * 75 + k],          f.Wih_s[(512 + ug) * 75 + k]);
      v.w = pack2(f.Wih_s[(1024 + ug) * 75 + k], f.Wih_s[(1536 + ug) * 75 + k]);
      WIHP[ug * 75 + k] = v;
    } else if (i < N1 + N2 + N3) {
      size_t j = i - N1 - N2; size_t ug = j / 75, k = j % 75;
      FTP[ug * 75 + k] = pack2(f.fct_w[ug * 75 + k], f.fc1_w[ug * 75 + k]);
    } else if (i < N1 + N2 + N3 + N4) {
      size_t j = i - N1 - N2 - N3; size_t ug = j / 75, k = j % 75;
      uint2 v;
      v.x = pack2(f.Wih_1[ug * 75 + k],          f.Wih_1[(512 + ug) * 75 + k]);
      v.y = pack2(f.Wih_1[(1024 + ug) * 75 + k], f.Wih_1[(1536 + ug) * 75 + k]);
      W1P[ug * 75 + k] = v;
    } else if (i < N1 + N2 + N3 + N4 + N5) {
      size_t j = i - N1 - N2 - N3 - N4; size_t qi = j >> 9, col = j & 511;
      float acc = 0.f;
      for (int n = 0; n < 512; ++n) acc = fmaf(f.U_s[col * 512 + n], f.fc2_w[qi * 512 + n], acc);
      U2[qi * 512 + col] = acc;
    } else {
      size_t qi = i - N1 - N2 - N3 - N4 - N5;
      float acc = f.fc2_b[qi];
      for (int n = 0; n < 512; ++n) acc = fmaf(f.b_us[n], f.fc2_w[qi * 512 + n], acc);
      B2[qi] = acc;
    }
  }
}

// ---------------- prep: initial state ----------------
__global__ __launch_bounds__(512) void prep_state(Full f) {
  const int b = blockIdx.x, j = threadIdx.x;
  __shared__ float x0[77];
  if (j < IN_) x0[j] = f.inputs[(size_t)b * T_ * IN_ + j];
  __syncthreads();
  float t1 = f.fct_b[j], t2 = f.fc1_b[j];
  for (int k = 0; k < IN_; ++k) {
    t1 = fmaf(x0[k], f.fct_w[j * IN_ + k], t1);
    t2 = fmaf(x0[k], f.fc1_w[j * IN_ + k], t2);
  }
  float4* SPA4 = (float4*)(f.ws + OFF_SPA);
  SPA4[(size_t)j * 128 + b] = make_float4(0.f, 0.f, t1, t2);
  ((float*)(f.ws + OFF_H1))[(((size_t)(j >> 1)) * 128 + b) * 2 + (j & 1)] = 0.f;
}

// register-staged prefetch chunk: 8 k's of state
struct Ch { float4 s[8]; float2 hp[4]; };

__device__ __forceinline__ void ldch(Ch& c, const float4* spc, const float2* h1p2,
                                     int kk, int bg) {
#pragma unroll
  for (int i = 0; i < 8; ++i) c.s[i] = spc[(size_t)(kk + i) * 128 + bg];
#pragma unroll
  for (int i = 0; i < 4; ++i) c.hp[i] = h1p2[(size_t)((kk >> 1) + i) * 128 + bg];
}

#define PAIR(c, kkc, p) { \
    const int kkp = (kkc) + 2 * (p); \
    const float4 s0 = (c).s[2 * (p)]; \
    const float4 s1 = (c).s[2 * (p) + 1]; \
    const float2 h1p = (c).hp[(p)]; \
    const float4 wt0 = *(const float4*)WhhL[0][kkp][u]; \
    const float4 wt1 = *(const float4*)WhhL[0][kkp + 1][u]; \
    const float4 wv0 = *(const float4*)WhhL[1][kkp][u]; \
    const float4 wv1 = *(const float4*)WhhL[1][kkp + 1][u]; \
    const float4 w10 = *(const float4*)WhhL[2][kkp][u]; \
    const float4 w11 = *(const float4*)WhhL[2][kkp + 1][u]; \
    const uint4 wx = WXL[kkp >> 1][u]; \
    at0 = fmaf(s0.x, wt0.x, at0); at1 = fmaf(s0.x, wt0.y, at1); \
    at2 = fmaf(s0.x, wt0.z, at2); at3 = fmaf(s0.x, wt0.w, at3); \
    at0 = fmaf(s1.x, wt1.x, at0); at1 = fmaf(s1.x, wt1.y, at1); \
    at2 = fmaf(s1.x, wt1.z, at2); at3 = fmaf(s1.x, wt1.w, at3); \
    as0 = fmaf(s0.y, wv0.x, as0); as1 = fmaf(s0.y, wv0.y, as1); \
    as2 = fmaf(s0.y, wv0.z, as2); as3 = fmaf(s0.y, wv0.w, as3); \
    as0 = fmaf(s1.y, wv1.x, as0); as1 = fmaf(s1.y, wv1.y, as1); \
    as2 = fmaf(s1.y, wv1.z, as2); as3 = fmaf(s1.y, wv1.w, as3); \
    g10 = fmaf(h1p.x, w10.x, g10); g11 = fmaf(h1p.x, w10.y, g11); \
    g12 = fmaf(h1p.x, w10.z, g12); g13 = fmaf(h1p.x, w10.w, g13); \
    g10 = fmaf(h1p.y, w11.x, g10); g11 = fmaf(h1p.y, w11.y, g11); \
    g12 = fmaf(h1p.y, w11.z, g12); g13 = fmaf(h1p.y, w11.w, g13); \
    aB = fmaf(s0.z, blo(wx.x), aB); aB = fmaf(s0.x, blo(wx.y), aB); \
    aB = fmaf(s1.z, bhi(wx.x), aB); aB = fmaf(s1.x, bhi(wx.y), aB); \
    aS = fmaf(s0.w, blo(wx.z), aS); aS = fmaf(s0.y, blo(wx.w), aS); \
    aS = fmaf(s1.w, bhi(wx.z), aS); aS = fmaf(s1.y, bhi(wx.w), aS); \
  }

#define CONSUME(c, kkc) { PAIR(c, kkc, 0) PAIR(c, kkc, 1) PAIR(c, kkc, 2) PAIR(c, kkc, 3) }

// ---------------- main persistent scan ----------------
__global__ __launch_bounds__(512, 1) void scan4(Full f) {
  const int tid = threadIdx.x, bid = blockIdx.x;
  const int h = tid >> 8;                 // k-half
  const int w = (tid >> 6) & 3, l = tid & 63;
  const int u = l & 3;                    // local unit 0..3
  const int bLrow = w * 16 + (l >> 2);    // local row 0..63
  const int bb = bid >> 7, bj = bid & 127;
  const int ug = bj * 4 + u;              // global unit
  const int bg = bb * 64 + bLrow;         // global batch row
  const int pid = (tid & 255);            // (u,bLrow) pair id

  char* wsb = f.ws;
  const uint4* WXTP = (const uint4*)(wsb + OFF_WXTP);
  const uint4* WIHP = (const uint4*)(wsb + OFF_WIHP);
  const unsigned* FTP = (const unsigned*)(wsb + OFF_FTP);
  const uint2* W1P = (const uint2*)(wsb + OFF_W1P);
  const float* U2 = (const float*)(wsb + OFF_U2);
  const float* B2 = (const float*)(wsb + OFF_B2);
  float4* SPA4 = (float4*)(wsb + OFF_SPA);
  float* H1f = (float*)(wsb + OFF_H1);
  const float2* H1p2 = (const float2*)(wsb + OFF_H1);
  float* ST = (float*)(wsb + OFF_ST);
  unsigned* FLG = (unsigned*)(wsb + OFF_FLG);

  float* out_logp = f.out;
  float* out_alpha = f.out + B_ * C_;
  float* out_beta = f.out + B_ * C_ + (size_t)T_ * B_ * Q_;

  // ---- LDS ----
  __shared__ float WhhL[3][512][4][4];    // [cell][k][u][gate] fp32   98304B
  __shared__ uint4 WXL[256][4];           // [k2][u]                   16384B
  __shared__ uint4 WihL[75][4];           // [k][u]                     4800B
  __shared__ unsigned FTL[75][4];         //                            1200B
  __shared__ uint2 W1L[75][4];            //                            2400B
  __shared__ unsigned short xcur[64][76]; // bf16 x rows                9728B
  __shared__ float redU[4352];            // reduce scratch            17408B
  __shared__ float alphaL[64][26];        //                            6656B

  // ---- stage weights into LDS (once) ----
  for (int c = 0; c < 3; ++c) {
    const float* W = (c == 0) ? f.Whh_t : (c == 1) ? f.Whh_s : f.Whh_1;
    for (int i = tid; i < 8192; i += 512) {
      int k = i & 511, gu = i >> 9, g = gu >> 2, uu = gu & 3;
      WhhL[c][k][uu][g] = W[((size_t)(g * 512 + bj * 4 + uu)) * 512 + k];
    }
  }
  for (int i = tid; i < 1024; i += 512) {
    int k2 = i >> 2, uu = i & 3;
    WXL[k2][uu] = WXTP[(size_t)(bj * 4 + uu) * 256 + k2];
  }
  for (int i = tid; i < 300; i += 512) {
    int k = i >> 2, uu = i & 3;
    WihL[k][uu] = WIHP[(size_t)(bj * 4 + uu) * 75 + k];
    FTL[k][uu] = FTP[(size_t)(bj * 4 + uu) * 75 + k];
    W1L[k][uu] = W1P[(size_t)(bj * 4 + uu) * 75 + k];
  }
  for (int i = tid; i < 64 * IN_; i += 512) {
    int r = i / IN_, k = i - r * IN_;
    xcur[r][k] = tob(f.inputs[((size_t)(bb * 64 + r) * T_) * IN_ + k]);
  }
  __syncthreads();

  // biases (indexed by ug)
  float btb0 = f.bih_t[ug] + f.bhh_t[ug];
  float btb1 = f.bih_t[512 + ug] + f.bhh_t[512 + ug];
  float btb2 = f.bih_t[1024 + ug] + f.bhh_t[1024 + ug];
  float btb3 = f.bih_t[1536 + ug] + f.bhh_t[1536 + ug];
  float bsb0 = f.bih_s[ug] + f.bhh_s[ug];
  float bsb1 = f.bih_s[512 + ug] + f.bhh_s[512 + ug];
  float bsb2 = f.bih_s[1024 + ug] + f.bhh_s[1024 + ug];
  float bsb3 = f.bih_s[1536 + ug] + f.bhh_s[1536 + ug];
  float b1b0 = f.bih_1[ug] + f.bhh_1[ug];
  float b1b1 = f.bih_1[512 + ug] + f.bhh_1[512 + ug];
  float b1b2 = f.bih_1[1024 + ug] + f.bhh_1[1024 + ug];
  float b1b3 = f.bih_1[1536 + ug] + f.bhh_1[1536 + ug];
  const float bB = f.b_s[ug] + f.b_t[ug];
  const float bS = f.b_s[ug];
  const float bT1 = f.fct_b[ug], bT2 = f.fc1_b[ug];

  float c_t = 0.f, c_s = 0.f, c1 = 0.f;
  unsigned bcount = 0;

  // barrier: flag store-release + parallel poll + single acquire
#define GBAR() do { \
    ++bcount; \
    __syncthreads(); \
    if (tid == 0) \
      __hip_atomic_store(&FLG[bid * 16], bcount, __ATOMIC_RELEASE, __HIP_MEMORY_SCOPE_AGENT); \
    if (tid < 256) { \
      while (__hip_atomic_load(&FLG[tid * 16], __ATOMIC_RELAXED, __HIP_MEMORY_SCOPE_AGENT) < bcount) \
        __builtin_amdgcn_s_sleep(1); \
    } \
    __syncthreads(); \
    (void)__hip_atomic_load(&FLG[0], __ATOMIC_ACQUIRE, __HIP_MEMORY_SCOPE_AGENT); \
  } while (0)

  for (int t = 0; t < T_; ++t) {
    // ================= phase A: all k-sums vs prev state =================
    float at0 = 0, at1 = 0, at2 = 0, at3 = 0;
    float as0 = 0, as1 = 0, as2 = 0, as3 = 0;
    float g10 = 0, g11 = 0, g12 = 0, g13 = 0;
    float aB = 0, aS = 0;
    const int kbase = h * 256;
    {
      Ch cA, cB;
      ldch(cA, SPA4, H1p2, kbase, bg);
#pragma unroll 1
      for (int it = 0; it < 16; ++it) {
        const int kk = kbase + it * 16;
        ldch(cB, SPA4, H1p2, kk + 8, bg);
        CONSUME(cA, kk);
        if (it < 15) ldch(cA, SPA4, H1p2, kk + 16, bg);
        CONSUME(cB, kk + 8);
      }
    }
    // x-part of gates_t / gates_s
    {
      const int kx0 = h ? 38 : 0, kx1 = h ? 75 : 38;
      for (int k = kx0; k < kx1; ++k) {
        const float xv = __uint_as_float((unsigned)xcur[bLrow][k] << 16);
        const uint4 wi = WihL[k][u];
        at0 = fmaf(xv, blo(wi.x), at0); at1 = fmaf(xv, bhi(wi.x), at1);
        at2 = fmaf(xv, blo(wi.y), at2); at3 = fmaf(xv, bhi(wi.y), at3);
        as0 = fmaf(xv, blo(wi.z), as0); as1 = fmaf(xv, bhi(wi.z), as1);
        as2 = fmaf(xv, blo(wi.w), as2); as3 = fmaf(xv, bhi(wi.w), as3);
      }
    }
    if (h) {
      float* rp = &redU[pid * 17];
      rp[0] = at0; rp[1] = at1; rp[2] = at2; rp[3] = at3;
      rp[4] = as0; rp[5] = as1; rp[6] = as2; rp[7] = as3;
      rp[8] = g10; rp[9] = g11; rp[10] = g12; rp[11] = g13;
      rp[12] = aB; rp[13] = aS;
    }
    __syncthreads();
    float htn = 0.f, hsn = 0.f, betav = 0.f;
    float gh0 = 0.f, gh1 = 0.f, gh2 = 0.f, gh3 = 0.f;
    if (!h) {
      const float* rp = &redU[pid * 17];
      at0 += rp[0]; at1 += rp[1]; at2 += rp[2]; at3 += rp[3];
      as0 += rp[4]; as1 += rp[5]; as2 += rp[6]; as3 += rp[7];
      g10 += rp[8]; g11 += rp[9]; g12 += rp[10]; g13 += rp[11];
      aB += rp[12]; aS += rp[13];
      const float it = sigm(at0 + btb0), ft = sigm(at1 + btb1);
      const float gt = tanhf(at2 + btb2), ot = sigm(at3 + btb3);
      c_t = ft * c_t + it * gt; htn = ot * tanhf(c_t);
      const float is = sigm(as0 + bsb0), fs = sigm(as1 + bsb1);
      const float gs = tanhf(as2 + bsb2), os = sigm(as3 + bsb3);
      c_s = fs * c_s + is * gs; hsn = os * tanhf(c_s);
      const float stv = tanhf(aS + bS);
      betav = fmaxf(aB + bB, 0.f);
      gh0 = g10 + b1b0; gh1 = g11 + b1b1; gh2 = g12 + b1b2; gh3 = g13 + b1b3;
      ST[(size_t)bg * 512 + ug] = stv;
    }
    GBAR();   // barrier 1: ST visible

    // ===== phase B' (in-block, redundant): alpha for this block's 64 rows =====
    {
      const float* stp = ST + (size_t)bg * 512 + h * 256 + u * 64;
      float4 sv[16];
#pragma unroll
      for (int i = 0; i < 16; ++i) sv[i] = *(const float4*)(stp + i * 4);
      const float* u2b = U2 + h * 256 + u * 64;
      for (int qi = 0; qi < 25; ++qi) {
        const float* up = u2b + qi * 512;
        float acc = 0.f;
#pragma unroll
        for (int i = 0; i < 16; ++i) {
          const float4 uv = *(const float4*)(up + i * 4);
          acc += sv[i].x * uv.x + sv[i].y * uv.y + sv[i].z * uv.z + sv[i].w * uv.w;
        }
        acc += __shfl_xor(acc, 1);
        acc += __shfl_xor(acc, 2);
        if (u == 0) redU[(h * 64 + bLrow) * 25 + qi] = acc;
      }
    }
    __syncthreads();
    if (tid < 64) {
      float q[25];
      float m = -1e30f;
#pragma unroll
      for (int qi = 0; qi < 25; ++qi) {
        q[qi] = B2[qi] + redU[tid * 25 + qi] + redU[(64 + tid) * 25 + qi];
        m = fmaxf(m, q[qi]);
      }
      float s = 0.f;
#pragma unroll
      for (int qi = 0; qi < 25; ++qi) { q[qi] = expf(q[qi] - m); s += q[qi]; }
      const float inv = 1.f / s;
#pragma unroll
      for (int qi = 0; qi < 25; ++qi) alphaL[tid][qi] = q[qi] * inv;
    }
    __syncthreads();
    if (bj == 0) {   // one block per row-half writes alpha out
      for (int i = tid; i < 64 * 25; i += 512) {
        const int r = i / 25, q = i - r * 25;
        out_alpha[((size_t)t * B_ + bb * 64 + r) * Q_ + q] = alphaL[r][q];
      }
    }

    // ================= phase C: cell1 + h1*beta + tmp-next =================
    float cx0 = 0, cx1 = 0, cx2 = 0, cx3 = 0;
    {
      const int q0 = h ? 13 : 0, q1 = h ? 25 : 13;
      for (int q = q0; q < q1; ++q) {
        const float av = alphaL[bLrow][q];
#pragma unroll
        for (int j = 0; j < 3; ++j) {
          const int k = q * 3 + j;
          const float xg = __uint_as_float((unsigned)xcur[bLrow][k] << 16) * av;
          const uint2 w1v = W1L[k][u];
          cx0 = fmaf(xg, blo(w1v.x), cx0); cx1 = fmaf(xg, bhi(w1v.x), cx1);
          cx2 = fmaf(xg, blo(w1v.y), cx2); cx3 = fmaf(xg, bhi(w1v.y), cx3);
        }
      }
    }
    if (h) {
      float* rp = &redU[pid * 17];
      rp[0] = cx0; rp[1] = cx1; rp[2] = cx2; rp[3] = cx3;
    }
    __syncthreads();
    // reload xcur <- x(t+1)
    if (t < T_ - 1) {
      for (int i = tid; i < 64 * IN_; i += 512) {
        const int r = i / IN_, k = i - r * IN_;
        xcur[r][k] = tob(f.inputs[((size_t)(bb * 64 + r) * T_ + (t + 1)) * IN_ + k]);
      }
    }
    __syncthreads();
    float aT1 = 0.f, aT2 = 0.f;
    if (t < T_ - 1) {
      const int kx0 = h ? 38 : 0, kx1 = h ? 75 : 38;
      for (int k = kx0; k < kx1; ++k) {
        const float xn = __uint_as_float((unsigned)xcur[bLrow][k] << 16);
        const unsigned ftv = FTL[k][u];
        aT1 = fmaf(xn, blo(ftv), aT1);
        aT2 = fmaf(xn, bhi(ftv), aT2);
      }
    }
    if (h) {
      float* rp = &redU[pid * 17];
      rp[14] = aT1; rp[15] = aT2;
    }
    __syncthreads();
    if (!h) {
      const float* rp = &redU[pid * 17];
      cx0 += rp[0]; cx1 += rp[1]; cx2 += rp[2]; cx3 += rp[3];
      const float t1n = aT1 + rp[14] + bT1;
      const float t2n = aT2 + rp[15] + bT2;
      const float i1 = sigm(cx0 + gh0), f1 = sigm(cx1 + gh1);
      const float gg = tanhf(cx2 + gh2), o1 = sigm(cx3 + gh3);
      c1 = f1 * c1 + i1 * gg;
      const float h1g = o1 * tanhf(c1) * betav;
      H1f[(((size_t)(ug >> 1)) * 128 + bg) * 2 + (ug & 1)] = h1g;
      if (t < T_ - 1) SPA4[(size_t)ug * 128 + bg] = make_float4(htn, hsn, t1n, t2n);
      out_beta[((size_t)t * B_ + bg) * H_ + ug] = betav;
    }
    GBAR();   // barrier 2: SPA/H1 visible for next step
  }

  // ================= epilogue: logits + log_softmax =================
  if (bid < 128) {
    const int r = bid;
    redU[tid] = H1f[(((size_t)(tid >> 1)) * 128 + r) * 2 + (tid & 1)];
    __syncthreads();
    if (tid < 480) {
      const int ci = tid >> 3, ks = tid & 7;
      const float* fr = f.fc_w + (size_t)ci * 512 + ks * 64;
      const float* hr = redU + ks * 64;
      float acc = 0.f;
      for (int j = 0; j < 64; j += 4) {
        const float4 fv = *(const float4*)(fr + j);
        const float4 hv = *(const float4*)(hr + j);
        acc += hv.x * fv.x + hv.y * fv.y + hv.z * fv.z + hv.w * fv.w;
      }
      redU[512 + ci * 8 + ks] = acc;
    }
    __syncthreads();
    if (tid < 60) {
      float s = f.fc_b[tid];
      for (int j = 0; j < 8; ++j) s += redU[512 + tid * 8 + j];
      redU[1024 + tid] = s;
    }
    __syncthreads();
    if (tid < 60) {
      float m = redU[1024];
      for (int i2 = 1; i2 < 60; ++i2) m = fmaxf(m, redU[1024 + i2]);
      float ssum = 0.f;
      for (int i2 = 0; i2 < 60; ++i2) ssum += expf(redU[1024 + i2] - m);
      out_logp[(size_t)r * C_ + tid] = redU[1024 + tid] - m - logf(ssum);
    }
  }
}

extern "C" void kernel_launch(void* const* d_in, const int* in_sizes, int n_in,
                              void* d_out, int out_size, void* d_ws, size_t ws_size,
                              hipStream_t stream) {
  if (ws_size < WS_BYTES) return;  // fail loudly (output stays poisoned)

  Full f;
  f.inputs = (const float*)d_in[0];
  f.Wih_t = (const float*)d_in[2];  f.Whh_t = (const float*)d_in[3];
  f.bih_t = (const float*)d_in[4];  f.bhh_t = (const float*)d_in[5];
  f.Wih_s = (const float*)d_in[6];  f.Whh_s = (const float*)d_in[7];
  f.bih_s = (const float*)d_in[8];  f.bhh_s = (const float*)d_in[9];
  f.Wih_1 = (const float*)d_in[10]; f.Whh_1 = (const float*)d_in[11];
  f.bih_1 = (const float*)d_in[12]; f.bhh_1 = (const float*)d_in[13];
  f.fc_w  = (const float*)d_in[14]; f.fc_b  = (const float*)d_in[15];
  f.fct_w = (const float*)d_in[16]; f.fct_b = (const float*)d_in[17];
  f.fc1_w = (const float*)d_in[18]; f.fc1_b = (const float*)d_in[19];
  f.fc2_w = (const float*)d_in[20]; f.fc2_b = (const float*)d_in[21];
  f.W_x_t = (const float*)d_in[22]; f.W_h_t = (const float*)d_in[23];
  f.b_t   = (const float*)d_in[24];
  f.W_x_s = (const float*)d_in[25]; f.W_h_s = (const float*)d_in[26];
  f.U_s   = (const float*)d_in[27]; f.b_s   = (const float*)d_in[28];
  f.b_us  = (const float*)d_in[29];
  f.ws = (char*)d_ws;
  f.out = (float*)d_out;

  hipLaunchKernelGGL(prep_pack, dim3(1024), dim3(256), 0, stream, f);
  hipLaunchKernelGGL(prep_state, dim3(128), dim3(512), 0, stream, f);

  void* args[] = { &f };
  hipLaunchCooperativeKernel((void*)scan4, dim3(256), dim3(512), args, 0, stream);
}

// Round 5
// 15591.779 us; speedup vs baseline: 1.5398x; 1.5398x over previous
//
#include <hip/hip_runtime.h>
#include <math.h>

#define B_ 128
#define T_ 128
#define IN_ 75
#define H_ 512
#define C_ 60
#define Q_ 25

// ---------------- workspace layout (bytes) ----------------
constexpr size_t OFF_WXTP = 0;         // uint4 [ug][k2] bf16 pairs {W_x_t,W_h_t,W_x_s,W_h_s} (lo=k,hi=k+1)
constexpr size_t OFF_WIHP = 2097152;   // uint4 [ug][k]  bf16 {it|ft, gt|ot, is|fs, gs|os}
constexpr size_t OFF_FTP  = 2711552;   // uint  [ug][k]  bf16 {fct|fc1}
constexpr size_t OFF_W1P  = 2865152;   // uint2 [ug][k]  bf16 {i1|f1, g1|o1}
constexpr size_t OFF_U2   = 3172352;   // float [25][512]  (U_s @ fc2_w.T)
constexpr size_t OFF_B2   = 3223552;   // float [32]
constexpr size_t OFF_SPA  = 3223680;   // float4 [k=unit][bg] {h_t,h_s,tmp1,tmp2}
constexpr size_t OFF_H1   = 4272256;   // float2 [k2][bg] {h1(2k2),h1(2k2+1)}
constexpr size_t OFF_ST   = 4534400;   // float [b][j]
constexpr size_t OFF_AL   = 4796544;   // float [b][25]
constexpr size_t OFF_FLG  = 4809344;   // unsigned flags, 256 x 64B, + GO word at index 4088
constexpr size_t WS_BYTES = 4825728;

struct Full {
  const float* inputs;
  const float* Wih_t; const float* Whh_t; const float* bih_t; const float* bhh_t;
  const float* Wih_s; const float* Whh_s; const float* bih_s; const float* bhh_s;
  const float* Wih_1; const float* Whh_1; const float* bih_1; const float* bhh_1;
  const float* fc_w;  const float* fc_b;
  const float* fct_w; const float* fct_b;
  const float* fc1_w; const float* fc1_b;
  const float* fc2_w; const float* fc2_b;
  const float* W_x_t; const float* W_h_t; const float* b_t;
  const float* W_x_s; const float* W_h_s; const float* U_s; const float* b_s; const float* b_us;
  char* ws; float* out;
};

__device__ __forceinline__ float sigm(float v) { return 1.f / (1.f + expf(-v)); }
__device__ __forceinline__ float blo(unsigned d) { return __uint_as_float(d << 16); }
__device__ __forceinline__ float bhi(unsigned d) { return __uint_as_float(d & 0xffff0000u); }
__device__ __forceinline__ unsigned short tob(float f) {
  unsigned u = __float_as_uint(f);
  return (unsigned short)((u + 0x7fffu + ((u >> 16) & 1u)) >> 16);
}
__device__ __forceinline__ unsigned pack2(float lo, float hi) {
  return (unsigned)tob(lo) | ((unsigned)tob(hi) << 16);
}

// ---------------- prep: pack weights ----------------
__global__ void prep_pack(Full f) {
  uint4* WXTP = (uint4*)(f.ws + OFF_WXTP);
  uint4* WIHP = (uint4*)(f.ws + OFF_WIHP);
  unsigned* FTP = (unsigned*)(f.ws + OFF_FTP);
  uint2* W1P = (uint2*)(f.ws + OFF_W1P);
  float* U2 = (float*)(f.ws + OFF_U2);
  float* B2 = (float*)(f.ws + OFF_B2);
  unsigned* FLG = (unsigned*)(f.ws + OFF_FLG);
  // zero barrier flags every launch (deterministic across graph replays)
  for (int i = blockIdx.x * blockDim.x + threadIdx.x; i < 4096; i += gridDim.x * blockDim.x)
    FLG[i] = 0u;

  const size_t N1 = (size_t)512 * 256;   // WXTP (ug,k2)
  const size_t N2 = (size_t)512 * 75;    // WIHP
  const size_t N3 = (size_t)512 * 75;    // FTP
  const size_t N4 = (size_t)512 * 75;    // W1P
  const size_t N5 = (size_t)25 * 512;    // U2
  const size_t N6 = 25;                  // B2
  const size_t TOT = N1 + N2 + N3 + N4 + N5 + N6;
  for (size_t i = (size_t)blockIdx.x * blockDim.x + threadIdx.x; i < TOT;
       i += (size_t)gridDim.x * blockDim.x) {
    if (i < N1) {
      size_t ug = i >> 8, k2 = i & 255; size_t k = k2 * 2;
      uint4 v;
      v.x = pack2(f.W_x_t[k * 512 + ug], f.W_x_t[(k + 1) * 512 + ug]);
      v.y = pack2(f.W_h_t[k * 512 + ug], f.W_h_t[(k + 1) * 512 + ug]);
      v.z = pack2(f.W_x_s[k * 512 + ug], f.W_x_s[(k + 1) * 512 + ug]);
      v.w = pack2(f.W_h_s[k * 512 + ug], f.W_h_s[(k + 1) * 512 + ug]);
      WXTP[ug * 256 + k2] = v;
    } else if (i < N1 + N2) {
      size_t j = i - N1; size_t ug = j / 75, k = j % 75;
      uint4 v;
      v.x = pack2(f.Wih_t[ug * 75 + k],          f.Wih_t[(512 + ug) * 75 + k]);
      v.y = pack2(f.Wih_t[(1024 + ug) * 75 + k], f.Wih_t[(1536 + ug) * 75 + k]);
      v.z = pack2(f.Wih_s[ug * 75 + k],          f.Wih_s[(512 + ug) * 75 + k]);
      v.w = pack2(f.Wih_s[(1024 + ug) * 75 + k], f.Wih_s[(1536 + ug) * 75 + k]);
      WIHP[ug * 75 + k] = v;
    } else if (i < N1 + N2 + N3) {
      size_t j = i - N1 - N2; size_t ug = j / 75, k = j % 75;
      FTP[ug * 75 + k] = pack2(f.fct_w[ug * 75 + k], f.fc1_w[ug * 75 + k]);
    } else if (i < N1 + N2 + N3 + N4) {
      size_t j = i - N1 - N2 - N3; size_t ug = j / 75, k = j % 75;
      uint2 v;
      v.x = pack2(f.Wih_1[ug * 75 + k],          f.Wih_1[(512 + ug) * 75 + k]);
      v.y = pack2(f.Wih_1[(1024 + ug) * 75 + k], f.Wih_1[(1536 + ug) * 75 + k]);
      W1P[ug * 75 + k] = v;
    } else if (i < N1 + N2 + N3 + N4 + N5) {
      size_t j = i - N1 - N2 - N3 - N4; size_t qi = j >> 9, col = j & 511;
      float acc = 0.f;
      for (int n = 0; n < 512; ++n) acc = fmaf(f.U_s[col * 512 + n], f.fc2_w[qi * 512 + n], acc);
      U2[qi * 512 + col] = acc;
    } else {
      size_t qi = i - N1 - N2 - N3 - N4 - N5;
      float acc = f.fc2_b[qi];
      for (int n = 0; n < 512; ++n) acc = fmaf(f.b_us[n], f.fc2_w[qi * 512 + n], acc);
      B2[qi] = acc;
    }
  }
}

// ---------------- prep: initial state ----------------
__global__ __launch_bounds__(512) void prep_state(Full f) {
  const int b = blockIdx.x, j = threadIdx.x;
  __shared__ float x0[77];
  if (j < IN_) x0[j] = f.inputs[(size_t)b * T_ * IN_ + j];
  __syncthreads();
  float t1 = f.fct_b[j], t2 = f.fc1_b[j];
  for (int k = 0; k < IN_; ++k) {
    t1 = fmaf(x0[k], f.fct_w[j * IN_ + k], t1);
    t2 = fmaf(x0[k], f.fc1_w[j * IN_ + k], t2);
  }
  float4* SPA4 = (float4*)(f.ws + OFF_SPA);
  SPA4[(size_t)j * 128 + b] = make_float4(0.f, 0.f, t1, t2);
  ((float*)(f.ws + OFF_H1))[(((size_t)(j >> 1)) * 128 + b) * 2 + (j & 1)] = 0.f;
}

// register-staged prefetch chunk: 8 k's of state
struct Ch { float4 s[8]; float2 hp[4]; };

__device__ __forceinline__ void ldch(Ch& c, const float4* spc, const float2* h1p2,
                                     int kk, int bg) {
#pragma unroll
  for (int i = 0; i < 8; ++i) c.s[i] = spc[(size_t)(kk + i) * 128 + bg];
#pragma unroll
  for (int i = 0; i < 4; ++i) c.hp[i] = h1p2[(size_t)((kk >> 1) + i) * 128 + bg];
}

#define PAIR(c, kkc, p) { \
    const int kkp = (kkc) + 2 * (p); \
    const float4 s0 = (c).s[2 * (p)]; \
    const float4 s1 = (c).s[2 * (p) + 1]; \
    const float2 h1p = (c).hp[(p)]; \
    const float4 wt0 = *(const float4*)WhhL[0][kkp][u]; \
    const float4 wt1 = *(const float4*)WhhL[0][kkp + 1][u]; \
    const float4 wv0 = *(const float4*)WhhL[1][kkp][u]; \
    const float4 wv1 = *(const float4*)WhhL[1][kkp + 1][u]; \
    const float4 w10 = *(const float4*)WhhL[2][kkp][u]; \
    const float4 w11 = *(const float4*)WhhL[2][kkp + 1][u]; \
    const uint4 wx = WXL[kkp >> 1][u]; \
    at0 = fmaf(s0.x, wt0.x, at0); at1 = fmaf(s0.x, wt0.y, at1); \
    at2 = fmaf(s0.x, wt0.z, at2); at3 = fmaf(s0.x, wt0.w, at3); \
    at0 = fmaf(s1.x, wt1.x, at0); at1 = fmaf(s1.x, wt1.y, at1); \
    at2 = fmaf(s1.x, wt1.z, at2); at3 = fmaf(s1.x, wt1.w, at3); \
    as0 = fmaf(s0.y, wv0.x, as0); as1 = fmaf(s0.y, wv0.y, as1); \
    as2 = fmaf(s0.y, wv0.z, as2); as3 = fmaf(s0.y, wv0.w, as3); \
    as0 = fmaf(s1.y, wv1.x, as0); as1 = fmaf(s1.y, wv1.y, as1); \
    as2 = fmaf(s1.y, wv1.z, as2); as3 = fmaf(s1.y, wv1.w, as3); \
    g10 = fmaf(h1p.x, w10.x, g10); g11 = fmaf(h1p.x, w10.y, g11); \
    g12 = fmaf(h1p.x, w10.z, g12); g13 = fmaf(h1p.x, w10.w, g13); \
    g10 = fmaf(h1p.y, w11.x, g10); g11 = fmaf(h1p.y, w11.y, g11); \
    g12 = fmaf(h1p.y, w11.z, g12); g13 = fmaf(h1p.y, w11.w, g13); \
    aB = fmaf(s0.z, blo(wx.x), aB); aB = fmaf(s0.x, blo(wx.y), aB); \
    aB = fmaf(s1.z, bhi(wx.x), aB); aB = fmaf(s1.x, bhi(wx.y), aB); \
    aS = fmaf(s0.w, blo(wx.z), aS); aS = fmaf(s0.y, blo(wx.w), aS); \
    aS = fmaf(s1.w, bhi(wx.z), aS); aS = fmaf(s1.y, bhi(wx.w), aS); \
  }

#define CONSUME(c, kkc) { PAIR(c, kkc, 0) PAIR(c, kkc, 1) PAIR(c, kkc, 2) PAIR(c, kkc, 3) }

// ---------------- main persistent scan ----------------
__global__ __launch_bounds__(512, 1) void scan5(Full f) {
  const int tid = threadIdx.x, bid = blockIdx.x;
  const int h = tid >> 8;                 // k-half
  const int w = (tid >> 6) & 3, l = tid & 63;
  const int u = l & 3;                    // local unit 0..3
  const int bLrow = w * 16 + (l >> 2);    // local row 0..63
  const int bb = bid >> 7, bj = bid & 127;
  const int ug = bj * 4 + u;              // global unit
  const int bg = bb * 64 + bLrow;         // global batch row
  const int pid = (tid & 255);            // (u,bLrow) pair id

  char* wsb = f.ws;
  const uint4* WXTP = (const uint4*)(wsb + OFF_WXTP);
  const uint4* WIHP = (const uint4*)(wsb + OFF_WIHP);
  const unsigned* FTP = (const unsigned*)(wsb + OFF_FTP);
  const uint2* W1P = (const uint2*)(wsb + OFF_W1P);
  const float* U2 = (const float*)(wsb + OFF_U2);
  const float* B2 = (const float*)(wsb + OFF_B2);
  float4* SPA4 = (float4*)(wsb + OFF_SPA);
  float* H1f = (float*)(wsb + OFF_H1);
  const float2* H1p2 = (const float2*)(wsb + OFF_H1);
  float* ST = (float*)(wsb + OFF_ST);
  float* ALPHA = (float*)(wsb + OFF_AL);
  unsigned* FLG = (unsigned*)(wsb + OFF_FLG);

  float* out_logp = f.out;
  float* out_alpha = f.out + B_ * C_;
  float* out_beta = f.out + B_ * C_ + (size_t)T_ * B_ * Q_;

  // ---- LDS ----
  __shared__ float WhhL[3][512][4][4];    // [cell][k][u][gate] fp32   98304B
  __shared__ uint4 WXL[256][4];           // [k2][u]                   16384B
  __shared__ uint4 WihL[75][4];           // [k][u]                     4800B
  __shared__ unsigned FTL[75][4];         //                            1200B
  __shared__ uint2 W1L[75][4];            //                            2400B
  __shared__ unsigned short xcur[64][76]; // bf16 x rows                9728B
  __shared__ float redU[4352];            // reduce / phase-B scratch  17408B
  __shared__ float alphaL[64][26];        //                            6656B

  // ---- stage weights into LDS (once) ----
  for (int c = 0; c < 3; ++c) {
    const float* W = (c == 0) ? f.Whh_t : (c == 1) ? f.Whh_s : f.Whh_1;
    for (int i = tid; i < 8192; i += 512) {
      int k = i & 511, gu = i >> 9, g = gu >> 2, uu = gu & 3;
      WhhL[c][k][uu][g] = W[((size_t)(g * 512 + bj * 4 + uu)) * 512 + k];
    }
  }
  for (int i = tid; i < 1024; i += 512) {
    int k2 = i >> 2, uu = i & 3;
    WXL[k2][uu] = WXTP[(size_t)(bj * 4 + uu) * 256 + k2];
  }
  for (int i = tid; i < 300; i += 512) {
    int k = i >> 2, uu = i & 3;
    WihL[k][uu] = WIHP[(size_t)(bj * 4 + uu) * 75 + k];
    FTL[k][uu] = FTP[(size_t)(bj * 4 + uu) * 75 + k];
    W1L[k][uu] = W1P[(size_t)(bj * 4 + uu) * 75 + k];
  }
  for (int i = tid; i < 64 * IN_; i += 512) {
    int r = i / IN_, k = i - r * IN_;
    xcur[r][k] = tob(f.inputs[((size_t)(bb * 64 + r) * T_) * IN_ + k]);
  }
  __syncthreads();

  // biases (indexed by ug)
  float btb0 = f.bih_t[ug] + f.bhh_t[ug];
  float btb1 = f.bih_t[512 + ug] + f.bhh_t[512 + ug];
  float btb2 = f.bih_t[1024 + ug] + f.bhh_t[1024 + ug];
  float btb3 = f.bih_t[1536 + ug] + f.bhh_t[1536 + ug];
  float bsb0 = f.bih_s[ug] + f.bhh_s[ug];
  float bsb1 = f.bih_s[512 + ug] + f.bhh_s[512 + ug];
  float bsb2 = f.bih_s[1024 + ug] + f.bhh_s[1024 + ug];
  float bsb3 = f.bih_s[1536 + ug] + f.bhh_s[1536 + ug];
  float b1b0 = f.bih_1[ug] + f.bhh_1[ug];
  float b1b1 = f.bih_1[512 + ug] + f.bhh_1[512 + ug];
  float b1b2 = f.bih_1[1024 + ug] + f.bhh_1[1024 + ug];
  float b1b3 = f.bih_1[1536 + ug] + f.bhh_1[1536 + ug];
  const float bB = f.b_s[ug] + f.b_t[ug];
  const float bS = f.b_s[ug];
  const float bT1 = f.fct_b[ug], bT2 = f.fc1_b[ug];

  float c_t = 0.f, c_s = 0.f, c1 = 0.f;
  unsigned bcount = 0;

  // leader-aggregated grid barrier:
  //   arrivals: parallel store-release to per-block padded flags
  //   block 0: 256 threads poll 256 flags in parallel, then store-release GO
  //   others: tid0 polls the single GO line; all threads acquire once
#define GBAR() do { \
    ++bcount; \
    __syncthreads(); \
    if (tid == 0) \
      __hip_atomic_store(&FLG[bid * 16], bcount, __ATOMIC_RELEASE, __HIP_MEMORY_SCOPE_AGENT); \
    if (bid == 0) { \
      if (tid < 256) { \
        while (__hip_atomic_load(&FLG[tid * 16], __ATOMIC_RELAXED, __HIP_MEMORY_SCOPE_AGENT) < bcount) \
          __builtin_amdgcn_s_sleep(2); \
      } \
      __syncthreads(); \
      if (tid == 0) \
        __hip_atomic_store(&FLG[4088], bcount, __ATOMIC_RELEASE, __HIP_MEMORY_SCOPE_AGENT); \
    } \
    if (tid == 0) { \
      while (__hip_atomic_load(&FLG[4088], __ATOMIC_RELAXED, __HIP_MEMORY_SCOPE_AGENT) < bcount) \
        __builtin_amdgcn_s_sleep(2); \
    } \
    __syncthreads(); \
    (void)__hip_atomic_load(&FLG[4088], __ATOMIC_ACQUIRE, __HIP_MEMORY_SCOPE_AGENT); \
  } while (0)

  for (int t = 0; t < T_; ++t) {
    // ================= phase A: all k-sums vs prev state =================
    float at0 = 0, at1 = 0, at2 = 0, at3 = 0;
    float as0 = 0, as1 = 0, as2 = 0, as3 = 0;
    float g10 = 0, g11 = 0, g12 = 0, g13 = 0;
    float aB = 0, aS = 0;
    const int kbase = h * 256;
    {
      Ch cA, cB;
      ldch(cA, SPA4, H1p2, kbase, bg);
#pragma unroll 1
      for (int it = 0; it < 16; ++it) {
        const int kk = kbase + it * 16;
        ldch(cB, SPA4, H1p2, kk + 8, bg);
        CONSUME(cA, kk);
        if (it < 15) ldch(cA, SPA4, H1p2, kk + 16, bg);
        CONSUME(cB, kk + 8);
      }
    }
    // x-part of gates_t / gates_s
    {
      const int kx0 = h ? 38 : 0, kx1 = h ? 75 : 38;
      for (int k = kx0; k < kx1; ++k) {
        const float xv = __uint_as_float((unsigned)xcur[bLrow][k] << 16);
        const uint4 wi = WihL[k][u];
        at0 = fmaf(xv, blo(wi.x), at0); at1 = fmaf(xv, bhi(wi.x), at1);
        at2 = fmaf(xv, blo(wi.y), at2); at3 = fmaf(xv, bhi(wi.y), at3);
        as0 = fmaf(xv, blo(wi.z), as0); as1 = fmaf(xv, bhi(wi.z), as1);
        as2 = fmaf(xv, blo(wi.w), as2); as3 = fmaf(xv, bhi(wi.w), as3);
      }
    }
    if (h) {
      float* rp = &redU[pid * 17];
      rp[0] = at0; rp[1] = at1; rp[2] = at2; rp[3] = at3;
      rp[4] = as0; rp[5] = as1; rp[6] = as2; rp[7] = as3;
      rp[8] = g10; rp[9] = g11; rp[10] = g12; rp[11] = g13;
      rp[12] = aB; rp[13] = aS;
    }
    __syncthreads();
    float htn = 0.f, hsn = 0.f, betav = 0.f;
    float gh0 = 0.f, gh1 = 0.f, gh2 = 0.f, gh3 = 0.f;
    if (!h) {
      const float* rp = &redU[pid * 17];
      at0 += rp[0]; at1 += rp[1]; at2 += rp[2]; at3 += rp[3];
      as0 += rp[4]; as1 += rp[5]; as2 += rp[6]; as3 += rp[7];
      g10 += rp[8]; g11 += rp[9]; g12 += rp[10]; g13 += rp[11];
      aB += rp[12]; aS += rp[13];
      const float it = sigm(at0 + btb0), ft = sigm(at1 + btb1);
      const float gt = tanhf(at2 + btb2), ot = sigm(at3 + btb3);
      c_t = ft * c_t + it * gt; htn = ot * tanhf(c_t);
      const float is = sigm(as0 + bsb0), fs = sigm(as1 + bsb1);
      const float gs = tanhf(as2 + bsb2), os = sigm(as3 + bsb3);
      c_s = fs * c_s + is * gs; hsn = os * tanhf(c_s);
      const float stv = tanhf(aS + bS);
      betav = fmaxf(aB + bB, 0.f);
      gh0 = g10 + b1b0; gh1 = g11 + b1b1; gh2 = g12 + b1b2; gh3 = g13 + b1b3;
      ST[(size_t)bg * 512 + ug] = stv;
    }
    GBAR();   // barrier 1: ST visible

    // ================= phase B: alpha softmax (128 blocks, 1 row each) =================
    if (bid < 128) {
      const int r = bid;
      float* stl = redU;            // [0..511]
      float* qp = redU + 512;       // [25*16]
      float* qv = redU + 1024;      // [25]
      stl[tid] = ST[(size_t)r * 512 + tid];
      __syncthreads();
      if (tid < 400) {
        const int qi = tid >> 4, ks = tid & 15;
        const float* u2p = U2 + (size_t)qi * 512 + ks * 32;
        const float* sp = stl + ks * 32;
        float acc = 0.f;
        for (int j = 0; j < 32; j += 4) {
          const float4 uv = *(const float4*)(u2p + j);
          const float4 sv = *(const float4*)(sp + j);
          acc += sv.x * uv.x + sv.y * uv.y + sv.z * uv.z + sv.w * uv.w;
        }
        qp[qi * 16 + ks] = acc;
      }
      __syncthreads();
      if (tid < 25) {
        float s = B2[tid];
        for (int j = 0; j < 16; ++j) s += qp[tid * 16 + j];
        qv[tid] = s;
      }
      __syncthreads();
      if (tid < 25) {
        float m = qv[0];
        for (int i2 = 1; i2 < 25; ++i2) m = fmaxf(m, qv[i2]);
        float s = 0.f;
        for (int i2 = 0; i2 < 25; ++i2) s += expf(qv[i2] - m);
        const float a = expf(qv[tid] - m) / s;
        ALPHA[(size_t)r * 25 + tid] = a;
        out_alpha[((size_t)t * B_ + r) * Q_ + tid] = a;
      }
    }
    GBAR();   // barrier 2: alpha visible

    // ================= phase C: cell1 + h1*beta + tmp-next =================
    for (int i = tid; i < 64 * 25; i += 512) {
      const int r = i / 25, q = i - r * 25;
      alphaL[r][q] = ALPHA[(size_t)(bb * 64 + r) * 25 + q];
    }
    __syncthreads();
    float cx0 = 0, cx1 = 0, cx2 = 0, cx3 = 0;
    {
      const int q0 = h ? 13 : 0, q1 = h ? 25 : 13;
      for (int q = q0; q < q1; ++q) {
        const float av = alphaL[bLrow][q];
#pragma unroll
        for (int j = 0; j < 3; ++j) {
          const int k = q * 3 + j;
          const float xg = __uint_as_float((unsigned)xcur[bLrow][k] << 16) * av;
          const uint2 w1v = W1L[k][u];
          cx0 = fmaf(xg, blo(w1v.x), cx0); cx1 = fmaf(xg, bhi(w1v.x), cx1);
          cx2 = fmaf(xg, blo(w1v.y), cx2); cx3 = fmaf(xg, bhi(w1v.y), cx3);
        }
      }
    }
    if (h) {
      float* rp = &redU[pid * 17];
      rp[0] = cx0; rp[1] = cx1; rp[2] = cx2; rp[3] = cx3;
    }
    __syncthreads();
    // reload xcur <- x(t+1)
    if (t < T_ - 1) {
      for (int i = tid; i < 64 * IN_; i += 512) {
        const int r = i / IN_, k = i - r * IN_;
        xcur[r][k] = tob(f.inputs[((size_t)(bb * 64 + r) * T_ + (t + 1)) * IN_ + k]);
      }
    }
    __syncthreads();
    float aT1 = 0.f, aT2 = 0.f;
    if (t < T_ - 1) {
      const int kx0 = h ? 38 : 0, kx1 = h ? 75 : 38;
      for (int k = kx0; k < kx1; ++k) {
        const float xn = __uint_as_float((unsigned)xcur[bLrow][k] << 16);
        const unsigned ftv = FTL[k][u];
        aT1 = fmaf(xn, blo(ftv), aT1);
        aT2 = fmaf(xn, bhi(ftv), aT2);
      }
    }
    if (h) {
      float* rp = &redU[pid * 17];
      rp[14] = aT1; rp[15] = aT2;
    }
    __syncthreads();
    if (!h) {
      const float* rp = &redU[pid * 17];
      cx0 += rp[0]; cx1 += rp[1]; cx2 += rp[2]; cx3 += rp[3];
      const float t1n = aT1 + rp[14] + bT1;
      const float t2n = aT2 + rp[15] + bT2;
      const float i1 = sigm(cx0 + gh0), f1 = sigm(cx1 + gh1);
      const float gg = tanhf(cx2 + gh2), o1 = sigm(cx3 + gh3);
      c1 = f1 * c1 + i1 * gg;
      const float h1g = o1 * tanhf(c1) * betav;
      H1f[(((size_t)(ug >> 1)) * 128 + bg) * 2 + (ug & 1)] = h1g;
      if (t < T_ - 1) SPA4[(size_t)ug * 128 + bg] = make_float4(htn, hsn, t1n, t2n);
      out_beta[((size_t)t * B_ + bg) * H_ + ug] = betav;
    }
    GBAR();   // barrier 3: SPA/H1 visible for next step
  }

  // ================= epilogue: logits + log_softmax =================
  if (bid < 128) {
    const int r = bid;
    redU[tid] = H1f[(((size_t)(tid >> 1)) * 128 + r) * 2 + (tid & 1)];
    __syncthreads();
    if (tid < 480) {
      const int ci = tid >> 3, ks = tid & 7;
      const float* fr = f.fc_w + (size_t)ci * 512 + ks * 64;
      const float* hr = redU + ks * 64;
      float acc = 0.f;
      for (int j = 0; j < 64; j += 4) {
        const float4 fv = *(const float4*)(fr + j);
        const float4 hv = *(const float4*)(hr + j);
        acc += hv.x * fv.x + hv.y * fv.y + hv.z * fv.z + hv.w * fv.w;
      }
      redU[512 + ci * 8 + ks] = acc;
    }
    __syncthreads();
    if (tid < 60) {
      float s = f.fc_b[tid];
      for (int j = 0; j < 8; ++j) s += redU[512 + tid * 8 + j];
      redU[1024 + tid] = s;
    }
    __syncthreads();
    if (tid < 60) {
      float m = redU[1024];
      for (int i2 = 1; i2 < 60; ++i2) m = fmaxf(m, redU[1024 + i2]);
      float ssum = 0.f;
      for (int i2 = 0; i2 < 60; ++i2) ssum += expf(redU[1024 + i2] - m);
      out_logp[(size_t)r * C_ + tid] = redU[1024 + tid] - m - logf(ssum);
    }
  }
}

extern "C" void kernel_launch(void* const* d_in, const int* in_sizes, int n_in,
                              void* d_out, int out_size, void* d_ws, size_t ws_size,
                              hipStream_t stream) {
  if (ws_size < WS_BYTES) return;  // fail loudly (output stays poisoned)

  Full f;
  f.inputs = (const float*)d_in[0];
  f.Wih_t = (const float*)d_in[2];  f.Whh_t = (const float*)d_in[3];
  f.bih_t = (const float*)d_in[4];  f.bhh_t = (const float*)d_in[5];
  f.Wih_s = (const float*)d_in[6];  f.Whh_s = (const float*)d_in[7];
  f.bih_s = (const float*)d_in[8];  f.bhh_s = (const float*)d_in[9];
  f.Wih_1 = (const float*)d_in[10]; f.Whh_1 = (const float*)d_in[11];
  f.bih_1 = (const float*)d_in[12]; f.bhh_1 = (const float*)d_in[13];
  f.fc_w  = (const float*)d_in[14]; f.fc_b  = (const float*)d_in[15];
  f.fct_w = (const float*)d_in[16]; f.fct_b = (const float*)d_in[17];
  f.fc1_w = (const float*)d_in[18]; f.fc1_b = (const float*)d_in[19];
  f.fc2_w = (const float*)d_in[20]; f.fc2_b = (const float*)d_in[21];
  f.W_x_t = (const float*)d_in[22]; f.W_h_t = (const float*)d_in[23];
  f.b_t   = (const float*)d_in[24];
  f.W_x_s = (const float*)d_in[25]; f.W_h_s = (const float*)d_in[26];
  f.U_s   = (const float*)d_in[27]; f.b_s   = (const float*)d_in[28];
  f.b_us  = (const float*)d_in[29];
  f.ws = (char*)d_ws;
  f.out = (float*)d_out;

  hipLaunchKernelGGL(prep_pack, dim3(1024), dim3(256), 0, stream, f);
  hipLaunchKernelGGL(prep_state, dim3(128), dim3(512), 0, stream, f);

  void* args[] = { &f };
  hipLaunchCooperativeKernel((void*)scan5, dim3(256), dim3(512), args, 0, stream);
}

// Round 6
// 10912.431 us; speedup vs baseline: 2.2001x; 1.4288x over previous
//
#include <hip/hip_runtime.h>
#include <math.h>

#define B_ 128
#define T_ 128
#define IN_ 75
#define H_ 512
#define C_ 60
#define Q_ 25

// ---------------- workspace layout (bytes) ----------------
constexpr size_t OFF_WXTP = 0;         // uint4 [ug][k2] bf16 pairs {W_x_t,W_h_t,W_x_s,W_h_s} (lo=k,hi=k+1)
constexpr size_t OFF_WIHP = 2097152;   // uint4 [ug][k]  bf16 {it|ft, gt|ot, is|fs, gs|os}
constexpr size_t OFF_FTP  = 2711552;   // uint  [ug][k]  bf16 {fct|fc1}
constexpr size_t OFF_W1P  = 2865152;   // uint2 [ug][k]  bf16 {i1|f1, g1|o1}
constexpr size_t OFF_U2   = 3172352;   // float [25][512]  (U_s @ fc2_w.T)
constexpr size_t OFF_B2   = 3223552;   // float [32]
constexpr size_t OFF_SPA  = 3223680;   // float4 [k=unit][bg] {h_t,h_s,tmp1,tmp2}
constexpr size_t OFF_H1   = 4272256;   // float2 [k2][bg] {h1(2k2),h1(2k2+1)}
constexpr size_t OFF_ST   = 4534400;   // float [b][j]
constexpr size_t OFF_AL   = 4796544;   // float [b][25]
constexpr size_t OFF_FLG  = 4809344;   // unsigned flags, 256 x 64B; GO word on its own line
constexpr size_t WS_BYTES = 4826752;

#define GO_IDX 4112                    // (4112*4 = byte 16448) own 64B line, past flag 255

struct Full {
  const float* inputs;
  const float* Wih_t; const float* Whh_t; const float* bih_t; const float* bhh_t;
  const float* Wih_s; const float* Whh_s; const float* bih_s; const float* bhh_s;
  const float* Wih_1; const float* Whh_1; const float* bih_1; const float* bhh_1;
  const float* fc_w;  const float* fc_b;
  const float* fct_w; const float* fct_b;
  const float* fc1_w; const float* fc1_b;
  const float* fc2_w; const float* fc2_b;
  const float* W_x_t; const float* W_h_t; const float* b_t;
  const float* W_x_s; const float* W_h_s; const float* U_s; const float* b_s; const float* b_us;
  char* ws; float* out;
};

__device__ __forceinline__ float sigm(float v) { return 1.f / (1.f + expf(-v)); }
__device__ __forceinline__ float blo(unsigned d) { return __uint_as_float(d << 16); }
__device__ __forceinline__ float bhi(unsigned d) { return __uint_as_float(d & 0xffff0000u); }
__device__ __forceinline__ unsigned short tob(float f) {
  unsigned u = __float_as_uint(f);
  return (unsigned short)((u + 0x7fffu + ((u >> 16) & 1u)) >> 16);
}
__device__ __forceinline__ unsigned pack2(float lo, float hi) {
  return (unsigned)tob(lo) | ((unsigned)tob(hi) << 16);
}

// ---------------- prep: pack weights ----------------
__global__ void prep_pack(Full f) {
  uint4* WXTP = (uint4*)(f.ws + OFF_WXTP);
  uint4* WIHP = (uint4*)(f.ws + OFF_WIHP);
  unsigned* FTP = (unsigned*)(f.ws + OFF_FTP);
  uint2* W1P = (uint2*)(f.ws + OFF_W1P);
  float* U2 = (float*)(f.ws + OFF_U2);
  float* B2 = (float*)(f.ws + OFF_B2);
  unsigned* FLG = (unsigned*)(f.ws + OFF_FLG);
  // zero barrier flags every launch (deterministic across graph replays)
  for (int i = blockIdx.x * blockDim.x + threadIdx.x; i < 4352; i += gridDim.x * blockDim.x)
    FLG[i] = 0u;

  const size_t N1 = (size_t)512 * 256;   // WXTP (ug,k2)
  const size_t N2 = (size_t)512 * 75;    // WIHP
  const size_t N3 = (size_t)512 * 75;    // FTP
  const size_t N4 = (size_t)512 * 75;    // W1P
  const size_t N5 = (size_t)25 * 512;    // U2
  const size_t N6 = 25;                  // B2
  const size_t TOT = N1 + N2 + N3 + N4 + N5 + N6;
  for (size_t i = (size_t)blockIdx.x * blockDim.x + threadIdx.x; i < TOT;
       i += (size_t)gridDim.x * blockDim.x) {
    if (i < N1) {
      size_t ug = i >> 8, k2 = i & 255; size_t k = k2 * 2;
      uint4 v;
      v.x = pack2(f.W_x_t[k * 512 + ug], f.W_x_t[(k + 1) * 512 + ug]);
      v.y = pack2(f.W_h_t[k * 512 + ug], f.W_h_t[(k + 1) * 512 + ug]);
      v.z = pack2(f.W_x_s[k * 512 + ug], f.W_x_s[(k + 1) * 512 + ug]);
      v.w = pack2(f.W_h_s[k * 512 + ug], f.W_h_s[(k + 1) * 512 + ug]);
      WXTP[ug * 256 + k2] = v;
    } else if (i < N1 + N2) {
      size_t j = i - N1; size_t ug = j / 75, k = j % 75;
      uint4 v;
      v.x = pack2(f.Wih_t[ug * 75 + k],          f.Wih_t[(512 + ug) * 75 + k]);
      v.y = pack2(f.Wih_t[(1024 + ug) * 75 + k], f.Wih_t[(1536 + ug) * 75 + k]);
      v.z = pack2(f.Wih_s[ug * 75 + k],          f.Wih_s[(512 + ug) * 75 + k]);
      v.w = pack2(f.Wih_s[(1024 + ug) * 75 + k], f.Wih_s[(1536 + ug) * 75 + k]);
      WIHP[ug * 75 + k] = v;
    } else if (i < N1 + N2 + N3) {
      size_t j = i - N1 - N2; size_t ug = j / 75, k = j % 75;
      FTP[ug * 75 + k] = pack2(f.fct_w[ug * 75 + k], f.fc1_w[ug * 75 + k]);
    } else if (i < N1 + N2 + N3 + N4) {
      size_t j = i - N1 - N2 - N3; size_t ug = j / 75, k = j % 75;
      uint2 v;
      v.x = pack2(f.Wih_1[ug * 75 + k],          f.Wih_1[(512 + ug) * 75 + k]);
      v.y = pack2(f.Wih_1[(1024 + ug) * 75 + k], f.Wih_1[(1536 + ug) * 75 + k]);
      W1P[ug * 75 + k] = v;
    } else if (i < N1 + N2 + N3 + N4 + N5) {
      size_t j = i - N1 - N2 - N3 - N4; size_t qi = j >> 9, col = j & 511;
      float acc = 0.f;
      for (int n = 0; n < 512; ++n) acc = fmaf(f.U_s[col * 512 + n], f.fc2_w[qi * 512 + n], acc);
      U2[qi * 512 + col] = acc;
    } else {
      size_t qi = i - N1 - N2 - N3 - N4 - N5;
      float acc = f.fc2_b[qi];
      for (int n = 0; n < 512; ++n) acc = fmaf(f.b_us[n], f.fc2_w[qi * 512 + n], acc);
      B2[qi] = acc;
    }
  }
}

// ---------------- prep: initial state ----------------
__global__ __launch_bounds__(512) void prep_state(Full f) {
  const int b = blockIdx.x, j = threadIdx.x;
  __shared__ float x0[77];
  if (j < IN_) x0[j] = f.inputs[(size_t)b * T_ * IN_ + j];
  __syncthreads();
  float t1 = f.fct_b[j], t2 = f.fc1_b[j];
  for (int k = 0; k < IN_; ++k) {
    t1 = fmaf(x0[k], f.fct_w[j * IN_ + k], t1);
    t2 = fmaf(x0[k], f.fc1_w[j * IN_ + k], t2);
  }
  float4* SPA4 = (float4*)(f.ws + OFF_SPA);
  SPA4[(size_t)j * 128 + b] = make_float4(0.f, 0.f, t1, t2);
  ((float*)(f.ws + OFF_H1))[(((size_t)(j >> 1)) * 128 + b) * 2 + (j & 1)] = 0.f;
}

// register-staged prefetch chunk: 8 k's of state
struct Ch { float4 s[8]; float2 hp[4]; };

__device__ __forceinline__ void ldch(Ch& c, const float4* spc, const float2* h1p2,
                                     int kk, int bg) {
#pragma unroll
  for (int i = 0; i < 8; ++i) c.s[i] = spc[(size_t)(kk + i) * 128 + bg];
#pragma unroll
  for (int i = 0; i < 4; ++i) c.hp[i] = h1p2[(size_t)((kk >> 1) + i) * 128 + bg];
}

#define PAIR(c, kkc, p) { \
    const int kkp = (kkc) + 2 * (p); \
    const float4 s0 = (c).s[2 * (p)]; \
    const float4 s1 = (c).s[2 * (p) + 1]; \
    const float2 h1p = (c).hp[(p)]; \
    const float4 wt0 = *(const float4*)WhhL[0][kkp][u]; \
    const float4 wt1 = *(const float4*)WhhL[0][kkp + 1][u]; \
    const float4 wv0 = *(const float4*)WhhL[1][kkp][u]; \
    const float4 wv1 = *(const float4*)WhhL[1][kkp + 1][u]; \
    const float4 w10 = *(const float4*)WhhL[2][kkp][u]; \
    const float4 w11 = *(const float4*)WhhL[2][kkp + 1][u]; \
    const uint4 wx = WXL[kkp >> 1][u]; \
    at0 = fmaf(s0.x, wt0.x, at0); at1 = fmaf(s0.x, wt0.y, at1); \
    at2 = fmaf(s0.x, wt0.z, at2); at3 = fmaf(s0.x, wt0.w, at3); \
    at0 = fmaf(s1.x, wt1.x, at0); at1 = fmaf(s1.x, wt1.y, at1); \
    at2 = fmaf(s1.x, wt1.z, at2); at3 = fmaf(s1.x, wt1.w, at3); \
    as0 = fmaf(s0.y, wv0.x, as0); as1 = fmaf(s0.y, wv0.y, as1); \
    as2 = fmaf(s0.y, wv0.z, as2); as3 = fmaf(s0.y, wv0.w, as3); \
    as0 = fmaf(s1.y, wv1.x, as0); as1 = fmaf(s1.y, wv1.y, as1); \
    as2 = fmaf(s1.y, wv1.z, as2); as3 = fmaf(s1.y, wv1.w, as3); \
    g10 = fmaf(h1p.x, w10.x, g10); g11 = fmaf(h1p.x, w10.y, g11); \
    g12 = fmaf(h1p.x, w10.z, g12); g13 = fmaf(h1p.x, w10.w, g13); \
    g10 = fmaf(h1p.y, w11.x, g10); g11 = fmaf(h1p.y, w11.y, g11); \
    g12 = fmaf(h1p.y, w11.z, g12); g13 = fmaf(h1p.y, w11.w, g13); \
    aB = fmaf(s0.z, blo(wx.x), aB); aB = fmaf(s0.x, blo(wx.y), aB); \
    aB = fmaf(s1.z, bhi(wx.x), aB); aB = fmaf(s1.x, bhi(wx.y), aB); \
    aS = fmaf(s0.w, blo(wx.z), aS); aS = fmaf(s0.y, blo(wx.w), aS); \
    aS = fmaf(s1.w, bhi(wx.z), aS); aS = fmaf(s1.y, bhi(wx.w), aS); \
  }

#define CONSUME(c, kkc) { PAIR(c, kkc, 0) PAIR(c, kkc, 1) PAIR(c, kkc, 2) PAIR(c, kkc, 3) }

// ---------------- main persistent scan ----------------
__global__ __launch_bounds__(512, 1) void scan6(Full f) {
  const int tid = threadIdx.x, bid = blockIdx.x;
  const int h = tid >> 8;                 // k-half
  const int w = (tid >> 6) & 3, l = tid & 63;
  const int u = l & 3;                    // local unit 0..3
  const int bLrow = w * 16 + (l >> 2);    // local row 0..63
  const int bb = bid >> 7, bj = bid & 127;
  const int ug = bj * 4 + u;              // global unit
  const int bg = bb * 64 + bLrow;         // global batch row
  const int pid = (tid & 255);            // (u,bLrow) pair id

  char* wsb = f.ws;
  const uint4* WXTP = (const uint4*)(wsb + OFF_WXTP);
  const uint4* WIHP = (const uint4*)(wsb + OFF_WIHP);
  const unsigned* FTP = (const unsigned*)(wsb + OFF_FTP);
  const uint2* W1P = (const uint2*)(wsb + OFF_W1P);
  const float* U2 = (const float*)(wsb + OFF_U2);
  const float* B2 = (const float*)(wsb + OFF_B2);
  float4* SPA4 = (float4*)(wsb + OFF_SPA);
  float* H1f = (float*)(wsb + OFF_H1);
  const float2* H1p2 = (const float2*)(wsb + OFF_H1);
  float* ST = (float*)(wsb + OFF_ST);
  float* ALPHA = (float*)(wsb + OFF_AL);
  unsigned* FLG = (unsigned*)(wsb + OFF_FLG);

  float* out_logp = f.out;
  float* out_alpha = f.out + B_ * C_;
  float* out_beta = f.out + B_ * C_ + (size_t)T_ * B_ * Q_;

  // ---- LDS ----
  __shared__ float WhhL[3][512][4][4];    // [cell][k][u][gate] fp32   98304B
  __shared__ uint4 WXL[256][4];           // [k2][u]                   16384B
  __shared__ uint4 WihL[75][4];           // [k][u]                     4800B
  __shared__ unsigned FTL[75][4];         //                            1200B
  __shared__ uint2 W1L[75][4];            //                            2400B
  __shared__ unsigned short xcur[64][76]; // bf16 x rows                9728B
  __shared__ float redU[4352];            // reduce / phase-B scratch  17408B
  __shared__ float alphaL[64][26];        //                            6656B

  // ---- stage weights into LDS (once) ----
  for (int c = 0; c < 3; ++c) {
    const float* W = (c == 0) ? f.Whh_t : (c == 1) ? f.Whh_s : f.Whh_1;
    for (int i = tid; i < 8192; i += 512) {
      int k = i & 511, gu = i >> 9, g = gu >> 2, uu = gu & 3;
      WhhL[c][k][uu][g] = W[((size_t)(g * 512 + bj * 4 + uu)) * 512 + k];
    }
  }
  for (int i = tid; i < 1024; i += 512) {
    int k2 = i >> 2, uu = i & 3;
    WXL[k2][uu] = WXTP[(size_t)(bj * 4 + uu) * 256 + k2];
  }
  for (int i = tid; i < 300; i += 512) {
    int k = i >> 2, uu = i & 3;
    WihL[k][uu] = WIHP[(size_t)(bj * 4 + uu) * 75 + k];
    FTL[k][uu] = FTP[(size_t)(bj * 4 + uu) * 75 + k];
    W1L[k][uu] = W1P[(size_t)(bj * 4 + uu) * 75 + k];
  }
  for (int i = tid; i < 64 * IN_; i += 512) {
    int r = i / IN_, k = i - r * IN_;
    xcur[r][k] = tob(f.inputs[((size_t)(bb * 64 + r) * T_) * IN_ + k]);
  }
  __syncthreads();

  // biases (indexed by ug)
  float btb0 = f.bih_t[ug] + f.bhh_t[ug];
  float btb1 = f.bih_t[512 + ug] + f.bhh_t[512 + ug];
  float btb2 = f.bih_t[1024 + ug] + f.bhh_t[1024 + ug];
  float btb3 = f.bih_t[1536 + ug] + f.bhh_t[1536 + ug];
  float bsb0 = f.bih_s[ug] + f.bhh_s[ug];
  float bsb1 = f.bih_s[512 + ug] + f.bhh_s[512 + ug];
  float bsb2 = f.bih_s[1024 + ug] + f.bhh_s[1024 + ug];
  float bsb3 = f.bih_s[1536 + ug] + f.bhh_s[1536 + ug];
  float b1b0 = f.bih_1[ug] + f.bhh_1[ug];
  float b1b1 = f.bih_1[512 + ug] + f.bhh_1[512 + ug];
  float b1b2 = f.bih_1[1024 + ug] + f.bhh_1[1024 + ug];
  float b1b3 = f.bih_1[1536 + ug] + f.bhh_1[1536 + ug];
  const float bB = f.b_s[ug] + f.b_t[ug];
  const float bS = f.b_s[ug];
  const float bT1 = f.fct_b[ug], bT2 = f.fc1_b[ug];

  float c_t = 0.f, c_s = 0.f, c1 = 0.f;
  unsigned bcount = 0;

  // leader-aggregated grid barrier; ONE acquire (cache invalidate) per block.
  // Release: tid0 store-release (one wbL2 per block; all block writes already
  // drained to L2 by the preceding __syncthreads). Acquire: tid0 performs the
  // single ACQUIRE load (buffer_inv/L1-inv are CU/XCD-wide physical ops, so one
  // wave's invalidate covers the whole block); __syncthreads orders the rest.
#define GBAR() do { \
    ++bcount; \
    __syncthreads(); \
    if (tid == 0) \
      __hip_atomic_store(&FLG[bid * 16], bcount, __ATOMIC_RELEASE, __HIP_MEMORY_SCOPE_AGENT); \
    if (bid == 0) { \
      if (tid < 256) { \
        while (__hip_atomic_load(&FLG[tid * 16], __ATOMIC_RELAXED, __HIP_MEMORY_SCOPE_AGENT) < bcount) \
          __builtin_amdgcn_s_sleep(2); \
      } \
      __syncthreads(); \
      if (tid == 0) \
        __hip_atomic_store(&FLG[GO_IDX], bcount, __ATOMIC_RELEASE, __HIP_MEMORY_SCOPE_AGENT); \
    } \
    if (tid == 0) { \
      while (__hip_atomic_load(&FLG[GO_IDX], __ATOMIC_RELAXED, __HIP_MEMORY_SCOPE_AGENT) < bcount) \
        __builtin_amdgcn_s_sleep(2); \
      (void)__hip_atomic_load(&FLG[GO_IDX], __ATOMIC_ACQUIRE, __HIP_MEMORY_SCOPE_AGENT); \
    } \
    __syncthreads(); \
  } while (0)

  for (int t = 0; t < T_; ++t) {
    // ================= phase A: all k-sums vs prev state =================
    float at0 = 0, at1 = 0, at2 = 0, at3 = 0;
    float as0 = 0, as1 = 0, as2 = 0, as3 = 0;
    float g10 = 0, g11 = 0, g12 = 0, g13 = 0;
    float aB = 0, aS = 0;
    const int kbase = h * 256;
    {
      Ch cA, cB;
      ldch(cA, SPA4, H1p2, kbase, bg);
#pragma unroll 1
      for (int it = 0; it < 16; ++it) {
        const int kk = kbase + it * 16;
        ldch(cB, SPA4, H1p2, kk + 8, bg);
        CONSUME(cA, kk);
        if (it < 15) ldch(cA, SPA4, H1p2, kk + 16, bg);
        CONSUME(cB, kk + 8);
      }
    }
    // x-part of gates_t / gates_s
    {
      const int kx0 = h ? 38 : 0, kx1 = h ? 75 : 38;
      for (int k = kx0; k < kx1; ++k) {
        const float xv = __uint_as_float((unsigned)xcur[bLrow][k] << 16);
        const uint4 wi = WihL[k][u];
        at0 = fmaf(xv, blo(wi.x), at0); at1 = fmaf(xv, bhi(wi.x), at1);
        at2 = fmaf(xv, blo(wi.y), at2); at3 = fmaf(xv, bhi(wi.y), at3);
        as0 = fmaf(xv, blo(wi.z), as0); as1 = fmaf(xv, bhi(wi.z), as1);
        as2 = fmaf(xv, blo(wi.w), as2); as3 = fmaf(xv, bhi(wi.w), as3);
      }
    }
    if (h) {
      float* rp = &redU[pid * 17];
      rp[0] = at0; rp[1] = at1; rp[2] = at2; rp[3] = at3;
      rp[4] = as0; rp[5] = as1; rp[6] = as2; rp[7] = as3;
      rp[8] = g10; rp[9] = g11; rp[10] = g12; rp[11] = g13;
      rp[12] = aB; rp[13] = aS;
    }
    __syncthreads();
    float htn = 0.f, hsn = 0.f, betav = 0.f;
    float gh0 = 0.f, gh1 = 0.f, gh2 = 0.f, gh3 = 0.f;
    if (!h) {
      const float* rp = &redU[pid * 17];
      at0 += rp[0]; at1 += rp[1]; at2 += rp[2]; at3 += rp[3];
      as0 += rp[4]; as1 += rp[5]; as2 += rp[6]; as3 += rp[7];
      g10 += rp[8]; g11 += rp[9]; g12 += rp[10]; g13 += rp[11];
      aB += rp[12]; aS += rp[13];
      const float it = sigm(at0 + btb0), ft = sigm(at1 + btb1);
      const float gt = tanhf(at2 + btb2), ot = sigm(at3 + btb3);
      c_t = ft * c_t + it * gt; htn = ot * tanhf(c_t);
      const float is = sigm(as0 + bsb0), fs = sigm(as1 + bsb1);
      const float gs = tanhf(as2 + bsb2), os = sigm(as3 + bsb3);
      c_s = fs * c_s + is * gs; hsn = os * tanhf(c_s);
      const float stv = tanhf(aS + bS);
      betav = fmaxf(aB + bB, 0.f);
      gh0 = g10 + b1b0; gh1 = g11 + b1b1; gh2 = g12 + b1b2; gh3 = g13 + b1b3;
      ST[(size_t)bg * 512 + ug] = stv;
    }
    GBAR();   // barrier 1: ST visible

    // ================= phase B: alpha softmax (128 blocks, 1 row each) =================
    if (bid < 128) {
      const int r = bid;
      float* stl = redU;            // [0..511]
      float* qp = redU + 512;       // [25*16]
      float* qv = redU + 1024;      // [25]
      stl[tid] = ST[(size_t)r * 512 + tid];
      __syncthreads();
      if (tid < 400) {
        const int qi = tid >> 4, ks = tid & 15;
        const float* u2p = U2 + (size_t)qi * 512 + ks * 32;
        const float* sp = stl + ks * 32;
        float acc = 0.f;
        for (int j = 0; j < 32; j += 4) {
          const float4 uv = *(const float4*)(u2p + j);
          const float4 sv = *(const float4*)(sp + j);
          acc += sv.x * uv.x + sv.y * uv.y + sv.z * uv.z + sv.w * uv.w;
        }
        qp[qi * 16 + ks] = acc;
      }
      __syncthreads();
      if (tid < 25) {
        float s = B2[tid];
        for (int j = 0; j < 16; ++j) s += qp[tid * 16 + j];
        qv[tid] = s;
      }
      __syncthreads();
      if (tid < 25) {
        float m = qv[0];
        for (int i2 = 1; i2 < 25; ++i2) m = fmaxf(m, qv[i2]);
        float s = 0.f;
        for (int i2 = 0; i2 < 25; ++i2) s += expf(qv[i2] - m);
        const float a = expf(qv[tid] - m) / s;
        ALPHA[(size_t)r * 25 + tid] = a;
        out_alpha[((size_t)t * B_ + r) * Q_ + tid] = a;
      }
    }
    GBAR();   // barrier 2: alpha visible

    // ================= phase C: cell1 + h1*beta + tmp-next =================
    for (int i = tid; i < 64 * 25; i += 512) {
      const int r = i / 25, q = i - r * 25;
      alphaL[r][q] = ALPHA[(size_t)(bb * 64 + r) * 25 + q];
    }
    __syncthreads();
    float cx0 = 0, cx1 = 0, cx2 = 0, cx3 = 0;
    {
      const int q0 = h ? 13 : 0, q1 = h ? 25 : 13;
      for (int q = q0; q < q1; ++q) {
        const float av = alphaL[bLrow][q];
#pragma unroll
        for (int j = 0; j < 3; ++j) {
          const int k = q * 3 + j;
          const float xg = __uint_as_float((unsigned)xcur[bLrow][k] << 16) * av;
          const uint2 w1v = W1L[k][u];
          cx0 = fmaf(xg, blo(w1v.x), cx0); cx1 = fmaf(xg, bhi(w1v.x), cx1);
          cx2 = fmaf(xg, blo(w1v.y), cx2); cx3 = fmaf(xg, bhi(w1v.y), cx3);
        }
      }
    }
    if (h) {
      float* rp = &redU[pid * 17];
      rp[0] = cx0; rp[1] = cx1; rp[2] = cx2; rp[3] = cx3;
    }
    __syncthreads();
    // reload xcur <- x(t+1)
    if (t < T_ - 1) {
      for (int i = tid; i < 64 * IN_; i += 512) {
        const int r = i / IN_, k = i - r * IN_;
        xcur[r][k] = tob(f.inputs[((size_t)(bb * 64 + r) * T_ + (t + 1)) * IN_ + k]);
      }
    }
    __syncthreads();
    float aT1 = 0.f, aT2 = 0.f;
    if (t < T_ - 1) {
      const int kx0 = h ? 38 : 0, kx1 = h ? 75 : 38;
      for (int k = kx0; k < kx1; ++k) {
        const float xn = __uint_as_float((unsigned)xcur[bLrow][k] << 16);
        const unsigned ftv = FTL[k][u];
        aT1 = fmaf(xn, blo(ftv), aT1);
        aT2 = fmaf(xn, bhi(ftv), aT2);
      }
    }
    if (h) {
      float* rp = &redU[pid * 17];
      rp[14] = aT1; rp[15] = aT2;
    }
    __syncthreads();
    if (!h) {
      const float* rp = &redU[pid * 17];
      cx0 += rp[0]; cx1 += rp[1]; cx2 += rp[2]; cx3 += rp[3];
      const float t1n = aT1 + rp[14] + bT1;
      const float t2n = aT2 + rp[15] + bT2;
      const float i1 = sigm(cx0 + gh0), f1 = sigm(cx1 + gh1);
      const float gg = tanhf(cx2 + gh2), o1 = sigm(cx3 + gh3);
      c1 = f1 * c1 + i1 * gg;
      const float h1g = o1 * tanhf(c1) * betav;
      H1f[(((size_t)(ug >> 1)) * 128 + bg) * 2 + (ug & 1)] = h1g;
      if (t < T_ - 1) SPA4[(size_t)ug * 128 + bg] = make_float4(htn, hsn, t1n, t2n);
      out_beta[((size_t)t * B_ + bg) * H_ + ug] = betav;
    }
    GBAR();   // barrier 3: SPA/H1 visible for next step
  }

  // ================= epilogue: logits + log_softmax =================
  if (bid < 128) {
    const int r = bid;
    redU[tid] = H1f[(((size_t)(tid >> 1)) * 128 + r) * 2 + (tid & 1)];
    __syncthreads();
    if (tid < 480) {
      const int ci = tid >> 3, ks = tid & 7;
      const float* fr = f.fc_w + (size_t)ci * 512 + ks * 64;
      const float* hr = redU + ks * 64;
      float acc = 0.f;
      for (int j = 0; j < 64; j += 4) {
        const float4 fv = *(const float4*)(fr + j);
        const float4 hv = *(const float4*)(hr + j);
        acc += hv.x * fv.x + hv.y * fv.y + hv.z * fv.z + hv.w * fv.w;
      }
      redU[512 + ci * 8 + ks] = acc;
    }
    __syncthreads();
    if (tid < 60) {
      float s = f.fc_b[tid];
      for (int j = 0; j < 8; ++j) s += redU[512 + tid * 8 + j];
      redU[1024 + tid] = s;
    }
    __syncthreads();
    if (tid < 60) {
      float m = redU[1024];
      for (int i2 = 1; i2 < 60; ++i2) m = fmaxf(m, redU[1024 + i2]);
      float ssum = 0.f;
      for (int i2 = 0; i2 < 60; ++i2) ssum += expf(redU[1024 + i2] - m);
      out_logp[(size_t)r * C_ + tid] = redU[1024 + tid] - m - logf(ssum);
    }
  }
}

extern "C" void kernel_launch(void* const* d_in, const int* in_sizes, int n_in,
                              void* d_out, int out_size, void* d_ws, size_t ws_size,
                              hipStream_t stream) {
  if (ws_size < WS_BYTES) return;  // fail loudly (output stays poisoned)

  Full f;
  f.inputs = (const float*)d_in[0];
  f.Wih_t = (const float*)d_in[2];  f.Whh_t = (const float*)d_in[3];
  f.bih_t = (const float*)d_in[4];  f.bhh_t = (const float*)d_in[5];
  f.Wih_s = (const float*)d_in[6];  f.Whh_s = (const float*)d_in[7];
  f.bih_s = (const float*)d_in[8];  f.bhh_s = (const float*)d_in[9];
  f.Wih_1 = (const float*)d_in[10]; f.Whh_1 = (const float*)d_in[11];
  f.bih_1 = (const float*)d_in[12]; f.bhh_1 = (const float*)d_in[13];
  f.fc_w  = (const float*)d_in[14]; f.fc_b  = (const float*)d_in[15];
  f.fct_w = (const float*)d_in[16]; f.fct_b = (const float*)d_in[17];
  f.fc1_w = (const float*)d_in[18]; f.fc1_b = (const float*)d_in[19];
  f.fc2_w = (const float*)d_in[20]; f.fc2_b = (const float*)d_in[21];
  f.W_x_t = (const float*)d_in[22]; f.W_h_t = (const float*)d_in[23];
  f.b_t   = (const float*)d_in[24];
  f.W_x_s = (const float*)d_in[25]; f.W_h_s = (const float*)d_in[26];
  f.U_s   = (const float*)d_in[27]; f.b_s   = (const float*)d_in[28];
  f.b_us  = (const float*)d_in[29];
  f.ws = (char*)d_ws;
  f.out = (float*)d_out;

  hipLaunchKernelGGL(prep_pack, dim3(1024), dim3(256), 0, stream, f);
  hipLaunchKernelGGL(prep_state, dim3(128), dim3(512), 0, stream, f);

  void* args[] = { &f };
  hipLaunchCooperativeKernel((void*)scan6, dim3(256), dim3(512), args, 0, stream);
}

// Round 7
// 10661.182 us; speedup vs baseline: 2.2520x; 1.0236x over previous
//
#include <hip/hip_runtime.h>
#include <math.h>

#define B_ 128
#define T_ 128
#define IN_ 75
#define H_ 512
#define C_ 60
#define Q_ 25

// ---------------- workspace layout (bytes) ----------------
constexpr size_t OFF_WXTP = 0;         // uint4 [ug][k2] bf16 pairs {W_x_t,W_h_t,W_x_s,W_h_s} (lo=k,hi=k+1)
constexpr size_t OFF_WIHP = 2097152;   // uint4 [ug][k]  bf16 {it|ft, gt|ot, is|fs, gs|os}
constexpr size_t OFF_FTP  = 2711552;   // uint  [ug][k]  bf16 {fct|fc1}
constexpr size_t OFF_W1P  = 2865152;   // uint2 [ug][k]  bf16 {i1|f1, g1|o1}
constexpr size_t OFF_U2   = 3172352;   // float [25][512]  (U_s @ fc2_w.T)
constexpr size_t OFF_B2   = 3223552;   // float [32]
constexpr size_t OFF_SPA  = 3223680;   // float4 [k=unit][bg] {h_t,h_s,tmp1,tmp2} (accessed as 2x float2 sc1)
constexpr size_t OFF_H1   = 4272256;   // float2 [k2][bg] {h1(2k2),h1(2k2+1)}
constexpr size_t OFF_ST   = 4534400;   // float [b][j]
constexpr size_t OFF_AL   = 4796544;   // float [b][25]
constexpr size_t OFF_FLG  = 4809344;   // unsigned flags, 256 x 64B; GO word on its own line
constexpr size_t WS_BYTES = 4826752;

#define GO_IDX 4112                    // own 64B line, past flag 255

struct Full {
  const float* inputs;
  const float* Wih_t; const float* Whh_t; const float* bih_t; const float* bhh_t;
  const float* Wih_s; const float* Whh_s; const float* bih_s; const float* bhh_s;
  const float* Wih_1; const float* Whh_1; const float* bih_1; const float* bhh_1;
  const float* fc_w;  const float* fc_b;
  const float* fct_w; const float* fct_b;
  const float* fc1_w; const float* fc1_b;
  const float* fc2_w; const float* fc2_b;
  const float* W_x_t; const float* W_h_t; const float* b_t;
  const float* W_x_s; const float* W_h_s; const float* U_s; const float* b_s; const float* b_us;
  char* ws; float* out;
};

__device__ __forceinline__ float sigm(float v) { return 1.f / (1.f + expf(-v)); }
__device__ __forceinline__ float blo(unsigned d) { return __uint_as_float(d << 16); }
__device__ __forceinline__ float bhi(unsigned d) { return __uint_as_float(d & 0xffff0000u); }
__device__ __forceinline__ unsigned short tob(float f) {
  unsigned u = __float_as_uint(f);
  return (unsigned short)((u + 0x7fffu + ((u >> 16) & 1u)) >> 16);
}
__device__ __forceinline__ unsigned pack2(float lo, float hi) {
  return (unsigned)tob(lo) | ((unsigned)tob(hi) << 16);
}

// device-coherent (L3-point, sc1) relaxed accessors — no L2 staleness, no
// release/acquire cache maintenance ever needed for this data.
__device__ __forceinline__ float2 lda2(const void* p) {
  unsigned long long v = __hip_atomic_load((const unsigned long long*)p,
                                           __ATOMIC_RELAXED, __HIP_MEMORY_SCOPE_AGENT);
  union { unsigned long long u; float2 f; } c; c.u = v; return c.f;
}
__device__ __forceinline__ void sta2(void* p, float2 x) {
  union { float2 f; unsigned long long u; } c; c.f = x;
  __hip_atomic_store((unsigned long long*)p, c.u, __ATOMIC_RELAXED, __HIP_MEMORY_SCOPE_AGENT);
}
__device__ __forceinline__ float lda1(const void* p) {
  unsigned v = __hip_atomic_load((const unsigned*)p, __ATOMIC_RELAXED, __HIP_MEMORY_SCOPE_AGENT);
  return __uint_as_float(v);
}
__device__ __forceinline__ void sta1(void* p, float x) {
  __hip_atomic_store((unsigned*)p, __float_as_uint(x), __ATOMIC_RELAXED, __HIP_MEMORY_SCOPE_AGENT);
}

// ---------------- prep: pack weights ----------------
__global__ void prep_pack(Full f) {
  uint4* WXTP = (uint4*)(f.ws + OFF_WXTP);
  uint4* WIHP = (uint4*)(f.ws + OFF_WIHP);
  unsigned* FTP = (unsigned*)(f.ws + OFF_FTP);
  uint2* W1P = (uint2*)(f.ws + OFF_W1P);
  float* U2 = (float*)(f.ws + OFF_U2);
  float* B2 = (float*)(f.ws + OFF_B2);
  unsigned* FLG = (unsigned*)(f.ws + OFF_FLG);
  // zero barrier flags every launch (deterministic across graph replays)
  for (int i = blockIdx.x * blockDim.x + threadIdx.x; i < 4352; i += gridDim.x * blockDim.x)
    FLG[i] = 0u;

  const size_t N1 = (size_t)512 * 256;   // WXTP (ug,k2)
  const size_t N2 = (size_t)512 * 75;    // WIHP
  const size_t N3 = (size_t)512 * 75;    // FTP
  const size_t N4 = (size_t)512 * 75;    // W1P
  const size_t N5 = (size_t)25 * 512;    // U2
  const size_t N6 = 25;                  // B2
  const size_t TOT = N1 + N2 + N3 + N4 + N5 + N6;
  for (size_t i = (size_t)blockIdx.x * blockDim.x + threadIdx.x; i < TOT;
       i += (size_t)gridDim.x * blockDim.x) {
    if (i < N1) {
      size_t ug = i >> 8, k2 = i & 255; size_t k = k2 * 2;
      uint4 v;
      v.x = pack2(f.W_x_t[k * 512 + ug], f.W_x_t[(k + 1) * 512 + ug]);
      v.y = pack2(f.W_h_t[k * 512 + ug], f.W_h_t[(k + 1) * 512 + ug]);
      v.z = pack2(f.W_x_s[k * 512 + ug], f.W_x_s[(k + 1) * 512 + ug]);
      v.w = pack2(f.W_h_s[k * 512 + ug], f.W_h_s[(k + 1) * 512 + ug]);
      WXTP[ug * 256 + k2] = v;
    } else if (i < N1 + N2) {
      size_t j = i - N1; size_t ug = j / 75, k = j % 75;
      uint4 v;
      v.x = pack2(f.Wih_t[ug * 75 + k],          f.Wih_t[(512 + ug) * 75 + k]);
      v.y = pack2(f.Wih_t[(1024 + ug) * 75 + k], f.Wih_t[(1536 + ug) * 75 + k]);
      v.z = pack2(f.Wih_s[ug * 75 + k],          f.Wih_s[(512 + ug) * 75 + k]);
      v.w = pack2(f.Wih_s[(1024 + ug) * 75 + k], f.Wih_s[(1536 + ug) * 75 + k]);
      WIHP[ug * 75 + k] = v;
    } else if (i < N1 + N2 + N3) {
      size_t j = i - N1 - N2; size_t ug = j / 75, k = j % 75;
      FTP[ug * 75 + k] = pack2(f.fct_w[ug * 75 + k], f.fc1_w[ug * 75 + k]);
    } else if (i < N1 + N2 + N3 + N4) {
      size_t j = i - N1 - N2 - N3; size_t ug = j / 75, k = j % 75;
      uint2 v;
      v.x = pack2(f.Wih_1[ug * 75 + k],          f.Wih_1[(512 + ug) * 75 + k]);
      v.y = pack2(f.Wih_1[(1024 + ug) * 75 + k], f.Wih_1[(1536 + ug) * 75 + k]);
      W1P[ug * 75 + k] = v;
    } else if (i < N1 + N2 + N3 + N4 + N5) {
      size_t j = i - N1 - N2 - N3 - N4; size_t qi = j >> 9, col = j & 511;
      float acc = 0.f;
      for (int n = 0; n < 512; ++n) acc = fmaf(f.U_s[col * 512 + n], f.fc2_w[qi * 512 + n], acc);
      U2[qi * 512 + col] = acc;
    } else {
      size_t qi = i - N1 - N2 - N3 - N4 - N5;
      float acc = f.fc2_b[qi];
      for (int n = 0; n < 512; ++n) acc = fmaf(f.b_us[n], f.fc2_w[qi * 512 + n], acc);
      B2[qi] = acc;
    }
  }
}

// ---------------- prep: initial state ----------------
__global__ __launch_bounds__(512) void prep_state(Full f) {
  const int b = blockIdx.x, j = threadIdx.x;
  __shared__ float x0[77];
  if (j < IN_) x0[j] = f.inputs[(size_t)b * T_ * IN_ + j];
  __syncthreads();
  float t1 = f.fct_b[j], t2 = f.fc1_b[j];
  for (int k = 0; k < IN_; ++k) {
    t1 = fmaf(x0[k], f.fct_w[j * IN_ + k], t1);
    t2 = fmaf(x0[k], f.fc1_w[j * IN_ + k], t2);
  }
  float4* SPA4 = (float4*)(f.ws + OFF_SPA);
  SPA4[(size_t)j * 128 + b] = make_float4(0.f, 0.f, t1, t2);
  ((float*)(f.ws + OFF_H1))[(((size_t)(j >> 1)) * 128 + b) * 2 + (j & 1)] = 0.f;
}

// register-staged prefetch chunk: 8 k's of state (sc1 coherent loads)
struct Ch { float4 s[8]; float2 hp[4]; };

__device__ __forceinline__ void ldch(Ch& c, const float2* sp2, const float2* h1p2,
                                     int kk, int bg) {
#pragma unroll
  for (int i = 0; i < 8; ++i) {
    const size_t e = ((size_t)(kk + i) * 128 + bg) * 2;
    const float2 lo = lda2(&sp2[e]);
    const float2 hi = lda2(&sp2[e + 1]);
    c.s[i] = make_float4(lo.x, lo.y, hi.x, hi.y);
  }
#pragma unroll
  for (int i = 0; i < 4; ++i) c.hp[i] = lda2(&h1p2[(size_t)((kk >> 1) + i) * 128 + bg]);
}

#define PAIR(c, kkc, p) { \
    const int kkp = (kkc) + 2 * (p); \
    const float4 s0 = (c).s[2 * (p)]; \
    const float4 s1 = (c).s[2 * (p) + 1]; \
    const float2 h1p = (c).hp[(p)]; \
    const float4 wt0 = *(const float4*)WhhL[0][kkp][u]; \
    const float4 wt1 = *(const float4*)WhhL[0][kkp + 1][u]; \
    const float4 wv0 = *(const float4*)WhhL[1][kkp][u]; \
    const float4 wv1 = *(const float4*)WhhL[1][kkp + 1][u]; \
    const float4 w10 = *(const float4*)WhhL[2][kkp][u]; \
    const float4 w11 = *(const float4*)WhhL[2][kkp + 1][u]; \
    const uint4 wx = WXL[kkp >> 1][u]; \
    at0 = fmaf(s0.x, wt0.x, at0); at1 = fmaf(s0.x, wt0.y, at1); \
    at2 = fmaf(s0.x, wt0.z, at2); at3 = fmaf(s0.x, wt0.w, at3); \
    at0 = fmaf(s1.x, wt1.x, at0); at1 = fmaf(s1.x, wt1.y, at1); \
    at2 = fmaf(s1.x, wt1.z, at2); at3 = fmaf(s1.x, wt1.w, at3); \
    as0 = fmaf(s0.y, wv0.x, as0); as1 = fmaf(s0.y, wv0.y, as1); \
    as2 = fmaf(s0.y, wv0.z, as2); as3 = fmaf(s0.y, wv0.w, as3); \
    as0 = fmaf(s1.y, wv1.x, as0); as1 = fmaf(s1.y, wv1.y, as1); \
    as2 = fmaf(s1.y, wv1.z, as2); as3 = fmaf(s1.y, wv1.w, as3); \
    g10 = fmaf(h1p.x, w10.x, g10); g11 = fmaf(h1p.x, w10.y, g11); \
    g12 = fmaf(h1p.x, w10.z, g12); g13 = fmaf(h1p.x, w10.w, g13); \
    g10 = fmaf(h1p.y, w11.x, g10); g11 = fmaf(h1p.y, w11.y, g11); \
    g12 = fmaf(h1p.y, w11.z, g12); g13 = fmaf(h1p.y, w11.w, g13); \
    aB = fmaf(s0.z, blo(wx.x), aB); aB = fmaf(s0.x, blo(wx.y), aB); \
    aB = fmaf(s1.z, bhi(wx.x), aB); aB = fmaf(s1.x, bhi(wx.y), aB); \
    aS = fmaf(s0.w, blo(wx.z), aS); aS = fmaf(s0.y, blo(wx.w), aS); \
    aS = fmaf(s1.w, bhi(wx.z), aS); aS = fmaf(s1.y, bhi(wx.w), aS); \
  }

#define CONSUME(c, kkc) { PAIR(c, kkc, 0) PAIR(c, kkc, 1) PAIR(c, kkc, 2) PAIR(c, kkc, 3) }

// ---------------- main persistent scan ----------------
__global__ __launch_bounds__(512, 1) void scan7(Full f) {
  const int tid = threadIdx.x, bid = blockIdx.x;
  const int h = tid >> 8;                 // k-half
  const int w = (tid >> 6) & 3, l = tid & 63;
  const int u = l & 3;                    // local unit 0..3
  const int bLrow = w * 16 + (l >> 2);    // local row 0..63
  const int bb = bid >> 7, bj = bid & 127;
  const int ug = bj * 4 + u;              // global unit
  const int bg = bb * 64 + bLrow;         // global batch row
  const int pid = (tid & 255);            // (u,bLrow) pair id

  char* wsb = f.ws;
  const uint4* WXTP = (const uint4*)(wsb + OFF_WXTP);
  const uint4* WIHP = (const uint4*)(wsb + OFF_WIHP);
  const unsigned* FTP = (const unsigned*)(wsb + OFF_FTP);
  const uint2* W1P = (const uint2*)(wsb + OFF_W1P);
  const float* U2 = (const float*)(wsb + OFF_U2);
  const float* B2 = (const float*)(wsb + OFF_B2);
  const float2* SP2 = (const float2*)(wsb + OFF_SPA);
  float2* SP2w = (float2*)(wsb + OFF_SPA);
  float* H1f = (float*)(wsb + OFF_H1);
  const float2* H1p2 = (const float2*)(wsb + OFF_H1);
  float* ST = (float*)(wsb + OFF_ST);
  float* ALPHA = (float*)(wsb + OFF_AL);
  unsigned* FLG = (unsigned*)(wsb + OFF_FLG);

  float* out_logp = f.out;
  float* out_alpha = f.out + B_ * C_;
  float* out_beta = f.out + B_ * C_ + (size_t)T_ * B_ * Q_;

  // ---- LDS ----
  __shared__ float WhhL[3][512][4][4];    // [cell][k][u][gate] fp32   98304B
  __shared__ uint4 WXL[256][4];           // [k2][u]                   16384B
  __shared__ uint4 WihL[75][4];           // [k][u]                     4800B
  __shared__ unsigned FTL[75][4];         //                            1200B
  __shared__ uint2 W1L[75][4];            //                            2400B
  __shared__ unsigned short xcur[64][76]; // bf16 x rows                9728B
  __shared__ float redU[4352];            // reduce / phase-B scratch  17408B
  __shared__ float alphaL[64][26];        //                            6656B

  // ---- stage weights into LDS (once) ----
  for (int c = 0; c < 3; ++c) {
    const float* W = (c == 0) ? f.Whh_t : (c == 1) ? f.Whh_s : f.Whh_1;
    for (int i = tid; i < 8192; i += 512) {
      int k = i & 511, gu = i >> 9, g = gu >> 2, uu = gu & 3;
      WhhL[c][k][uu][g] = W[((size_t)(g * 512 + bj * 4 + uu)) * 512 + k];
    }
  }
  for (int i = tid; i < 1024; i += 512) {
    int k2 = i >> 2, uu = i & 3;
    WXL[k2][uu] = WXTP[(size_t)(bj * 4 + uu) * 256 + k2];
  }
  for (int i = tid; i < 300; i += 512) {
    int k = i >> 2, uu = i & 3;
    WihL[k][uu] = WIHP[(size_t)(bj * 4 + uu) * 75 + k];
    FTL[k][uu] = FTP[(size_t)(bj * 4 + uu) * 75 + k];
    W1L[k][uu] = W1P[(size_t)(bj * 4 + uu) * 75 + k];
  }
  for (int i = tid; i < 64 * IN_; i += 512) {
    int r = i / IN_, k = i - r * IN_;
    xcur[r][k] = tob(f.inputs[((size_t)(bb * 64 + r) * T_) * IN_ + k]);
  }
  __syncthreads();

  // biases (indexed by ug)
  float btb0 = f.bih_t[ug] + f.bhh_t[ug];
  float btb1 = f.bih_t[512 + ug] + f.bhh_t[512 + ug];
  float btb2 = f.bih_t[1024 + ug] + f.bhh_t[1024 + ug];
  float btb3 = f.bih_t[1536 + ug] + f.bhh_t[1536 + ug];
  float bsb0 = f.bih_s[ug] + f.bhh_s[ug];
  float bsb1 = f.bih_s[512 + ug] + f.bhh_s[512 + ug];
  float bsb2 = f.bih_s[1024 + ug] + f.bhh_s[1024 + ug];
  float bsb3 = f.bih_s[1536 + ug] + f.bhh_s[1536 + ug];
  float b1b0 = f.bih_1[ug] + f.bhh_1[ug];
  float b1b1 = f.bih_1[512 + ug] + f.bhh_1[512 + ug];
  float b1b2 = f.bih_1[1024 + ug] + f.bhh_1[1024 + ug];
  float b1b3 = f.bih_1[1536 + ug] + f.bhh_1[1536 + ug];
  const float bB = f.b_s[ug] + f.b_t[ug];
  const float bS = f.b_s[ug];
  const float bT1 = f.fct_b[ug], bT2 = f.fc1_b[ug];

  float c_t = 0.f, c_s = 0.f, c1 = 0.f;
  unsigned bcount = 0;

  // pure-signaling grid barrier: ZERO release/acquire cache maintenance.
  // All cross-block state uses sc1 (L3-point) accessors, so correctness only
  // needs (a) each wave's sc1 stores complete (vmcnt 0) before arrival, and
  // (b) in-order issue after the poll (HW guarantees; __syncthreads fences the
  // compiler).
#define GBAR() do { \
    ++bcount; \
    asm volatile("s_waitcnt vmcnt(0) lgkmcnt(0)" ::: "memory"); \
    __syncthreads(); \
    if (tid == 0) \
      __hip_atomic_store(&FLG[bid * 16], bcount, __ATOMIC_RELAXED, __HIP_MEMORY_SCOPE_AGENT); \
    if (bid == 0) { \
      if (tid < 256) { \
        while (__hip_atomic_load(&FLG[tid * 16], __ATOMIC_RELAXED, __HIP_MEMORY_SCOPE_AGENT) < bcount) \
          __builtin_amdgcn_s_sleep(2); \
      } \
      __syncthreads(); \
      if (tid == 0) \
        __hip_atomic_store(&FLG[GO_IDX], bcount, __ATOMIC_RELAXED, __HIP_MEMORY_SCOPE_AGENT); \
    } \
    if (tid == 0) { \
      while (__hip_atomic_load(&FLG[GO_IDX], __ATOMIC_RELAXED, __HIP_MEMORY_SCOPE_AGENT) < bcount) \
        __builtin_amdgcn_s_sleep(2); \
    } \
    __syncthreads(); \
  } while (0)

  for (int t = 0; t < T_; ++t) {
    // ================= phase A: all k-sums vs prev state =================
    float at0 = 0, at1 = 0, at2 = 0, at3 = 0;
    float as0 = 0, as1 = 0, as2 = 0, as3 = 0;
    float g10 = 0, g11 = 0, g12 = 0, g13 = 0;
    float aB = 0, aS = 0;
    const int kbase = h * 256;
    {
      Ch cA, cB;
      ldch(cA, SP2, H1p2, kbase, bg);
#pragma unroll 1
      for (int it = 0; it < 16; ++it) {
        const int kk = kbase + it * 16;
        ldch(cB, SP2, H1p2, kk + 8, bg);
        CONSUME(cA, kk);
        if (it < 15) ldch(cA, SP2, H1p2, kk + 16, bg);
        CONSUME(cB, kk + 8);
      }
    }
    // x-part of gates_t / gates_s
    {
      const int kx0 = h ? 38 : 0, kx1 = h ? 75 : 38;
      for (int k = kx0; k < kx1; ++k) {
        const float xv = __uint_as_float((unsigned)xcur[bLrow][k] << 16);
        const uint4 wi = WihL[k][u];
        at0 = fmaf(xv, blo(wi.x), at0); at1 = fmaf(xv, bhi(wi.x), at1);
        at2 = fmaf(xv, blo(wi.y), at2); at3 = fmaf(xv, bhi(wi.y), at3);
        as0 = fmaf(xv, blo(wi.z), as0); as1 = fmaf(xv, bhi(wi.z), as1);
        as2 = fmaf(xv, blo(wi.w), as2); as3 = fmaf(xv, bhi(wi.w), as3);
      }
    }
    if (h) {
      float* rp = &redU[pid * 17];
      rp[0] = at0; rp[1] = at1; rp[2] = at2; rp[3] = at3;
      rp[4] = as0; rp[5] = as1; rp[6] = as2; rp[7] = as3;
      rp[8] = g10; rp[9] = g11; rp[10] = g12; rp[11] = g13;
      rp[12] = aB; rp[13] = aS;
    }
    __syncthreads();
    float htn = 0.f, hsn = 0.f, betav = 0.f;
    float gh0 = 0.f, gh1 = 0.f, gh2 = 0.f, gh3 = 0.f;
    if (!h) {
      const float* rp = &redU[pid * 17];
      at0 += rp[0]; at1 += rp[1]; at2 += rp[2]; at3 += rp[3];
      as0 += rp[4]; as1 += rp[5]; as2 += rp[6]; as3 += rp[7];
      g10 += rp[8]; g11 += rp[9]; g12 += rp[10]; g13 += rp[11];
      aB += rp[12]; aS += rp[13];
      const float it = sigm(at0 + btb0), ft = sigm(at1 + btb1);
      const float gt = tanhf(at2 + btb2), ot = sigm(at3 + btb3);
      c_t = ft * c_t + it * gt; htn = ot * tanhf(c_t);
      const float is = sigm(as0 + bsb0), fs = sigm(as1 + bsb1);
      const float gs = tanhf(as2 + bsb2), os = sigm(as3 + bsb3);
      c_s = fs * c_s + is * gs; hsn = os * tanhf(c_s);
      const float stv = tanhf(aS + bS);
      betav = fmaxf(aB + bB, 0.f);
      gh0 = g10 + b1b0; gh1 = g11 + b1b1; gh2 = g12 + b1b2; gh3 = g13 + b1b3;
      sta1(&ST[(size_t)bg * 512 + ug], stv);
    }
    GBAR();   // barrier 1: ST visible

    // ================= phase B: alpha softmax (128 blocks, 1 row each) =================
    if (bid < 128) {
      const int r = bid;
      float* stl = redU;            // [0..511]
      float* qp = redU + 512;       // [25*16]
      float* qv = redU + 1024;      // [25]
      stl[tid] = lda1(&ST[(size_t)r * 512 + tid]);
      __syncthreads();
      if (tid < 400) {
        const int qi = tid >> 4, ks = tid & 15;
        const float* u2p = U2 + (size_t)qi * 512 + ks * 32;
        const float* sp = stl + ks * 32;
        float acc = 0.f;
        for (int j = 0; j < 32; j += 4) {
          const float4 uv = *(const float4*)(u2p + j);
          const float4 sv = *(const float4*)(sp + j);
          acc += sv.x * uv.x + sv.y * uv.y + sv.z * uv.z + sv.w * uv.w;
        }
        qp[qi * 16 + ks] = acc;
      }
      __syncthreads();
      if (tid < 25) {
        float s = B2[tid];
        for (int j = 0; j < 16; ++j) s += qp[tid * 16 + j];
        qv[tid] = s;
      }
      __syncthreads();
      if (tid < 25) {
        float m = qv[0];
        for (int i2 = 1; i2 < 25; ++i2) m = fmaxf(m, qv[i2]);
        float s = 0.f;
        for (int i2 = 0; i2 < 25; ++i2) s += expf(qv[i2] - m);
        const float a = expf(qv[tid] - m) / s;
        sta1(&ALPHA[(size_t)r * 25 + tid], a);
        out_alpha[((size_t)t * B_ + r) * Q_ + tid] = a;
      }
    }
    GBAR();   // barrier 2: alpha visible

    // ================= phase C: cell1 + h1*beta + tmp-next =================
    for (int i = tid; i < 64 * 25; i += 512) {
      const int r = i / 25, q = i - r * 25;
      alphaL[r][q] = lda1(&ALPHA[(size_t)(bb * 64 + r) * 25 + q]);
    }
    __syncthreads();
    float cx0 = 0, cx1 = 0, cx2 = 0, cx3 = 0;
    {
      const int q0 = h ? 13 : 0, q1 = h ? 25 : 13;
      for (int q = q0; q < q1; ++q) {
        const float av = alphaL[bLrow][q];
#pragma unroll
        for (int j = 0; j < 3; ++j) {
          const int k = q * 3 + j;
          const float xg = __uint_as_float((unsigned)xcur[bLrow][k] << 16) * av;
          const uint2 w1v = W1L[k][u];
          cx0 = fmaf(xg, blo(w1v.x), cx0); cx1 = fmaf(xg, bhi(w1v.x), cx1);
          cx2 = fmaf(xg, blo(w1v.y), cx2); cx3 = fmaf(xg, bhi(w1v.y), cx3);
        }
      }
    }
    if (h) {
      float* rp = &redU[pid * 17];
      rp[0] = cx0; rp[1] = cx1; rp[2] = cx2; rp[3] = cx3;
    }
    __syncthreads();
    // reload xcur <- x(t+1)
    if (t < T_ - 1) {
      for (int i = tid; i < 64 * IN_; i += 512) {
        const int r = i / IN_, k = i - r * IN_;
        xcur[r][k] = tob(f.inputs[((size_t)(bb * 64 + r) * T_ + (t + 1)) * IN_ + k]);
      }
    }
    __syncthreads();
    float aT1 = 0.f, aT2 = 0.f;
    if (t < T_ - 1) {
      const int kx0 = h ? 38 : 0, kx1 = h ? 75 : 38;
      for (int k = kx0; k < kx1; ++k) {
        const float xn = __uint_as_float((unsigned)xcur[bLrow][k] << 16);
        const unsigned ftv = FTL[k][u];
        aT1 = fmaf(xn, blo(ftv), aT1);
        aT2 = fmaf(xn, bhi(ftv), aT2);
      }
    }
    if (h) {
      float* rp = &redU[pid * 17];
      rp[14] = aT1; rp[15] = aT2;
    }
    __syncthreads();
    if (!h) {
      const float* rp = &redU[pid * 17];
      cx0 += rp[0]; cx1 += rp[1]; cx2 += rp[2]; cx3 += rp[3];
      const float t1n = aT1 + rp[14] + bT1;
      const float t2n = aT2 + rp[15] + bT2;
      const float i1 = sigm(cx0 + gh0), f1 = sigm(cx1 + gh1);
      const float gg = tanhf(cx2 + gh2), o1 = sigm(cx3 + gh3);
      c1 = f1 * c1 + i1 * gg;
      const float h1g = o1 * tanhf(c1) * betav;
      sta1(&H1f[(((size_t)(ug >> 1)) * 128 + bg) * 2 + (ug & 1)], h1g);
      if (t < T_ - 1) {
        const size_t e = ((size_t)ug * 128 + bg) * 2;
        sta2(&SP2w[e], make_float2(htn, hsn));
        sta2(&SP2w[e + 1], make_float2(t1n, t2n));
      }
      out_beta[((size_t)t * B_ + bg) * H_ + ug] = betav;
    }
    GBAR();   // barrier 3: SPA/H1 visible for next step
  }

  // ================= epilogue: logits + log_softmax =================
  if (bid < 128) {
    const int r = bid;
    redU[tid] = lda1(&H1f[(((size_t)(tid >> 1)) * 128 + r) * 2 + (tid & 1)]);
    __syncthreads();
    if (tid < 480) {
      const int ci = tid >> 3, ks = tid & 7;
      const float* fr = f.fc_w + (size_t)ci * 512 + ks * 64;
      const float* hr = redU + ks * 64;
      float acc = 0.f;
      for (int j = 0; j < 64; j += 4) {
        const float4 fv = *(const float4*)(fr + j);
        const float4 hv = *(const float4*)(hr + j);
        acc += hv.x * fv.x + hv.y * fv.y + hv.z * fv.z + hv.w * fv.w;
      }
      redU[512 + ci * 8 + ks] = acc;
    }
    __syncthreads();
    if (tid < 60) {
      float s = f.fc_b[tid];
      for (int j = 0; j < 8; ++j) s += redU[512 + tid * 8 + j];
      redU[1024 + tid] = s;
    }
    __syncthreads();
    if (tid < 60) {
      float m = redU[1024];
      for (int i2 = 1; i2 < 60; ++i2) m = fmaxf(m, redU[1024 + i2]);
      float ssum = 0.f;
      for (int i2 = 0; i2 < 60; ++i2) ssum += expf(redU[1024 + i2] - m);
      out_logp[(size_t)r * C_ + tid] = redU[1024 + tid] - m - logf(ssum);
    }
  }
}

extern "C" void kernel_launch(void* const* d_in, const int* in_sizes, int n_in,
                              void* d_out, int out_size, void* d_ws, size_t ws_size,
                              hipStream_t stream) {
  if (ws_size < WS_BYTES) return;  // fail loudly (output stays poisoned)

  Full f;
  f.inputs = (const float*)d_in[0];
  f.Wih_t = (const float*)d_in[2];  f.Whh_t = (const float*)d_in[3];
  f.bih_t = (const float*)d_in[4];  f.bhh_t = (const float*)d_in[5];
  f.Wih_s = (const float*)d_in[6];  f.Whh_s = (const float*)d_in[7];
  f.bih_s = (const float*)d_in[8];  f.bhh_s = (const float*)d_in[9];
  f.Wih_1 = (const float*)d_in[10]; f.Whh_1 = (const float*)d_in[11];
  f.bih_1 = (const float*)d_in[12]; f.bhh_1 = (const float*)d_in[13];
  f.fc_w  = (const float*)d_in[14]; f.fc_b  = (const float*)d_in[15];
  f.fct_w = (const float*)d_in[16]; f.fct_b = (const float*)d_in[17];
  f.fc1_w = (const float*)d_in[18]; f.fc1_b = (const float*)d_in[19];
  f.fc2_w = (const float*)d_in[20]; f.fc2_b = (const float*)d_in[21];
  f.W_x_t = (const float*)d_in[22]; f.W_h_t = (const float*)d_in[23];
  f.b_t   = (const float*)d_in[24];
  f.W_x_s = (const float*)d_in[25]; f.W_h_s = (const float*)d_in[26];
  f.U_s   = (const float*)d_in[27]; f.b_s   = (const float*)d_in[28];
  f.b_us  = (const float*)d_in[29];
  f.ws = (char*)d_ws;
  f.out = (float*)d_out;

  hipLaunchKernelGGL(prep_pack, dim3(1024), dim3(256), 0, stream, f);
  hipLaunchKernelGGL(prep_state, dim3(128), dim3(512), 0, stream, f);

  void* args[] = { &f };
  hipLaunchCooperativeKernel((void*)scan7, dim3(256), dim3(512), args, 0, stream);
}